// Round 1
// baseline (884.575 us; speedup 1.0000x reference)
//
#include <hip/hip_runtime.h>
#include <hip/hip_bf16.h>

typedef __hip_bfloat16 bf16;
typedef unsigned short ushort_t;

#define T_  1024
#define D_  2048
#define H_  32
#define HD_ 64
#define NTRI_ 136   // 16*17/2 lower-triangular tile pairs

static const size_t TT_ = (size_t)T_ * T_;
static const size_t TD_ = (size_t)T_ * D_;

__device__ __forceinline__ ushort_t f2bf(float v) {
    bf16 b = __float2bfloat16(v);
    return *(ushort_t*)&b;
}
__device__ __forceinline__ float bf2f(ushort_t u) {
    bf16 b = *(bf16*)&u;
    return __bfloat162float(b);
}

typedef __attribute__((ext_vector_type(8))) short frag8;
typedef __attribute__((ext_vector_type(4))) float f32x4;
typedef __attribute__((ext_vector_type(4))) unsigned short u16x4;
typedef __attribute__((ext_vector_type(8))) unsigned short u16x8;

#define MFMA16(a, b, c) __builtin_amdgcn_mfma_f32_16x16x32_bf16((a), (b), (c), 0, 0, 0)

// ---------------------------------------------------------------------------
// MFMA GEMM: C = A[M,K]bf16 @ Bt[N,K]^T. 128x128 tile, BK=32.
// OUT: 0 = f32 row-major [M,N]
//      3 = packed QKV+small: col<2048 -> qh head-major bf16; <4096 -> kh;
//          <6144 -> vt transposed [head][64][T]; >=6144 -> Cout2 f32 [M][128]
// ---------------------------------------------------------------------------
template <int OUT>
__global__ __launch_bounds__(256) void mfma_gemm(
    const ushort_t* __restrict__ A, const ushort_t* __restrict__ Bt,
    void* __restrict__ Cout, void* __restrict__ Cout2, int M, int N, int K)
{
    __shared__ short Al[128 * 32];
    __shared__ short Bl[128 * 32];
    int tid = threadIdx.x;
    int w = tid >> 6, l = tid & 63;
    int row0 = blockIdx.y * 128, col0 = blockIdx.x * 128;
    int mq = (w >> 1) * 64, nq = (w & 1) * 64;
    int lm = l & 15, kq = l >> 4;
    f32x4 acc[4][4] = {};
    const ushort_t* Ap = A + (size_t)row0 * K;
    const ushort_t* Bp = Bt + (size_t)col0 * K;
    for (int kk = 0; kk < K; kk += 32) {
        __syncthreads();
#pragma unroll
        for (int r = 0; r < 2; r++) {
            int c = r * 256 + w * 64 + l;
            int row = c >> 2, kc = (c & 3) * 8;
            const ushort_t* ga = Ap + (size_t)row * K + kk + kc;
            const ushort_t* gb = Bp + (size_t)row * K + kk + kc;
            short* la = Al + (size_t)(r * 256 + w * 64) * 8;
            short* lb = Bl + (size_t)(r * 256 + w * 64) * 8;
            __builtin_amdgcn_global_load_lds((const __attribute__((address_space(1))) void*)ga,
                                             (__attribute__((address_space(3))) void*)la, 16, 0, 0);
            __builtin_amdgcn_global_load_lds((const __attribute__((address_space(1))) void*)gb,
                                             (__attribute__((address_space(3))) void*)lb, 16, 0, 0);
        }
        __builtin_amdgcn_s_waitcnt(0);
        __syncthreads();
        frag8 af[4], bfg[4];
#pragma unroll
        for (int i = 0; i < 4; i++)
            af[i] = *(const frag8*)&Al[(size_t)(mq + i * 16 + lm) * 32 + kq * 8];
#pragma unroll
        for (int j = 0; j < 4; j++)
            bfg[j] = *(const frag8*)&Bl[(size_t)(nq + j * 16 + lm) * 32 + kq * 8];
#pragma unroll
        for (int i = 0; i < 4; i++)
#pragma unroll
            for (int j = 0; j < 4; j++)
                acc[i][j] = MFMA16(af[i], bfg[j], acc[i][j]);
    }
#pragma unroll
    for (int i = 0; i < 4; i++)
#pragma unroll
        for (int j = 0; j < 4; j++)
#pragma unroll
            for (int r = 0; r < 4; r++) {
                int row = row0 + mq + i * 16 + kq * 4 + r;
                int col = col0 + nq + j * 16 + lm;
                float v = acc[i][j][r];
                if (OUT == 0) {
                    ((float*)Cout)[(size_t)row * N + col] = v;
                } else {
                    ushort_t* q = (ushort_t*)Cout;
                    int which = col >> 11, cl = col & 2047;
                    int hd = cl >> 6, d = cl & 63;
                    if (which == 0)
                        q[((size_t)hd * M + row) * 64 + d] = f2bf(v);
                    else if (which == 1)
                        q[(size_t)M * 2048 + ((size_t)hd * M + row) * 64 + d] = f2bf(v);
                    else if (which == 2)
                        q[(size_t)M * 4096 + ((size_t)hd * 64 + d) * M + row] = f2bf(v);
                    else
                        ((float*)Cout2)[(size_t)row * 128 + (col - 6144)] = v;
                }
            }
}

// ---------------------------------------------------------------------------
__global__ void transpose_convert(const float* __restrict__ W, ushort_t* __restrict__ Wt,
                                  int R, int Cc)
{
    __shared__ float tile[32][33];
    int bx = blockIdx.x * 32, by = blockIdx.y * 32;
    int tx = threadIdx.x, ty = threadIdx.y;
    for (int i = ty; i < 32; i += 8)
        tile[i][tx] = W[(size_t)(by + i) * Cc + bx + tx];
    __syncthreads();
    for (int i = ty; i < 32; i += 8)
        Wt[(size_t)(bx + i) * R + by + tx] = f2bf(tile[tx][i]);
}

// pack Ww1^T/Wbt^T/Wg^T (+zero pad) into rows [0..128) of dst[128][2048]
__global__ void pack96(const float* __restrict__ Ww1, const float* __restrict__ Wbt,
                       const float* __restrict__ Wg, ushort_t* __restrict__ dst)
{
    int r = blockIdx.x;
    int k = blockIdx.y * 256 + threadIdx.x;
    float v = 0.f;
    if (r < 32)       v = Ww1[(size_t)k * 32 + r];
    else if (r < 64)  v = Wbt[(size_t)k * 32 + (r - 32)];
    else if (r < 96)  v = Wg[(size_t)k * 32 + (r - 64)];
    dst[(size_t)r * 2048 + k] = f2bf(v);
}

__global__ void convert_bf16(const float* __restrict__ in, ushort_t* __restrict__ out, int n)
{
    int i = blockIdx.x * 256 + threadIdx.x;
    if (i < n) out[i] = f2bf(in[i]);
}

// epilogue of the 96-proj: w1 bf16, beta, G(pre-scan)
__global__ void bg96(const float* __restrict__ s96, const float* __restrict__ bbt,
                     const float* __restrict__ bgp, ushort_t* __restrict__ w1bf,
                     float* __restrict__ betaB, float* __restrict__ Gb)
{
    int idx = blockIdx.x * 256 + threadIdx.x;   // over T_*128
    int t = idx >> 7, o = idx & 127;
    if (o >= 96) return;
    float v = s96[(size_t)t * 128 + o];
    if (o < 32) {
        w1bf[(size_t)t * 32 + o] = f2bf(v);
    } else if (o < 64) {
        float xb = v + bbt[o - 32];
        betaB[(size_t)t * H_ + (o - 32)] = 2.f / (1.f + expf(-xb));
    } else {
        float xg = v + bgp[o - 64];
        Gb[(size_t)t * H_ + (o - 64)] =
            (xg >= 0.f) ? -log1pf(expf(-xg)) : (xg - log1pf(expf(xg)));
    }
}

// parallel inclusive scan of G[:, h] per head. Grid (H_), block 256.
__global__ void scan_g(float* __restrict__ G)
{
    int h = blockIdx.x;
    int tid = threadIdx.x;
    __shared__ float psum[256];
    float v[4];
    float s = 0.f;
#pragma unroll
    for (int r = 0; r < 4; r++) {
        v[r] = G[(size_t)(tid * 4 + r) * H_ + h];
        s += v[r];
    }
    psum[tid] = s;
    __syncthreads();
    for (int off = 1; off < 256; off <<= 1) {
        float t = (tid >= off) ? psum[tid - off] : 0.f;
        __syncthreads();
        psum[tid] += t;
        __syncthreads();
    }
    float run = (tid > 0) ? psum[tid - 1] : 0.f;
#pragma unroll
    for (int r = 0; r < 4; r++) {
        run += v[r];
        G[(size_t)(tid * 4 + r) * H_ + h] = run;
    }
}

// conv(3) + silu + l2norm -> wh bf16 head-major [H][T][64]
__global__ void conv_silu_norm(const float* __restrict__ wr, const float* __restrict__ convw,
                               ushort_t* __restrict__ wh)
{
    int b = blockIdx.x;
    int t = b >> 5, h = b & 31;
    int d = threadIdx.x;
    int c = h * 64 + d;
    float c0 = convw[c * 3 + 0];
    float c1 = convw[c * 3 + 1];
    float c2 = convw[c * 3 + 2];
    float x = c2 * wr[(size_t)t * D_ + c];
    if (t >= 1) x += c1 * wr[(size_t)(t - 1) * D_ + c];
    if (t >= 2) x += c0 * wr[(size_t)(t - 2) * D_ + c];
    float y = x / (1.f + expf(-x));
    float ss = y * y;
    for (int off = 32; off > 0; off >>= 1) ss += __shfl_xor(ss, off, 64);
    wh[((size_t)h * T_ + t) * 64 + d] = f2bf(y * rsqrtf(ss));
}

// ---------------------------------------------------------------------------
// pairdotLC: per lower tile (t0,s0):
//   L[t][s]  = strict(w_t.w_s)*beta[s]   (bf16 row-major, into ELb)
//   Ct[s][t] = strict(w_t.k_s)           (bf16 TRANSPOSED [s][t])
// ---------------------------------------------------------------------------
__global__ __launch_bounds__(256) void pairdotLC(
    const ushort_t* __restrict__ kh, const ushort_t* __restrict__ wh,
    const float* __restrict__ betaB,
    ushort_t* __restrict__ ELb, ushort_t* __restrict__ Ct, int hs)
{
    int s0 = blockIdx.x * 64, t0 = blockIdx.y * 64, z = blockIdx.z;
    if (s0 > t0) return;
    int head = hs + z;
    const ushort_t* kb = kh + (size_t)head * T_ * 64;
    const ushort_t* wb = wh + (size_t)head * T_ * 64;
    ushort_t* Lz = ELb + (size_t)z * TT_;
    ushort_t* Cz = Ct + (size_t)z * TT_;
    int tid = threadIdx.x;
    int w = tid >> 6, l = tid & 63;
    int lm = l & 15, kq = l >> 4;
    int rowA = t0 + w * 16 + lm;
    f32x4 accL[4] = {}, accS[4] = {};
#pragma unroll
    for (int kk = 0; kk < 64; kk += 32) {
        frag8 aw = *(const frag8*)&wb[(size_t)rowA * 64 + kk + kq * 8];
#pragma unroll
        for (int j = 0; j < 4; j++) {
            int colr = s0 + j * 16 + lm;
            frag8 bw = *(const frag8*)&wb[(size_t)colr * 64 + kk + kq * 8];
            frag8 bk = *(const frag8*)&kb[(size_t)colr * 64 + kk + kq * 8];
            accL[j] = MFMA16(aw, bw, accL[j]);
            accS[j] = MFMA16(aw, bk, accS[j]);
        }
    }
    int m0 = w * 16 + kq * 4;
#pragma unroll
    for (int j = 0; j < 4; j++) {
        int s = s0 + j * 16 + lm;
        float beta = betaB[(size_t)s * H_ + head];
        ushort_t cl[4];
#pragma unroll
        for (int r = 0; r < 4; r++) {
            int t = t0 + m0 + r;
            Lz[(size_t)t * T_ + s] = f2bf((s < t) ? accL[j][r] * beta : 0.f);
            cl[r] = f2bf((s < t) ? accS[j][r] : 0.f);
        }
        *(u16x4*)&Cz[(size_t)s * T_ + t0 + m0] = *(u16x4*)cl;
    }
}

// pairdotE: Em[t][s] = -causal(q_t.w_s)*beta[s] into ELb (L dead post-solve)
__global__ __launch_bounds__(256) void pairdotE(
    const ushort_t* __restrict__ qh, const ushort_t* __restrict__ wh,
    const float* __restrict__ betaB, ushort_t* __restrict__ ELb, int hs)
{
    int s0 = blockIdx.x * 64, t0 = blockIdx.y * 64, z = blockIdx.z;
    if (s0 > t0) return;
    int head = hs + z;
    const ushort_t* qb = qh + (size_t)head * T_ * 64;
    const ushort_t* wb = wh + (size_t)head * T_ * 64;
    ushort_t* Ez = ELb + (size_t)z * TT_;
    int tid = threadIdx.x;
    int w = tid >> 6, l = tid & 63;
    int lm = l & 15, kq = l >> 4;
    int rowA = t0 + w * 16 + lm;
    f32x4 accE[4] = {};
#pragma unroll
    for (int kk = 0; kk < 64; kk += 32) {
        frag8 aq = *(const frag8*)&qb[(size_t)rowA * 64 + kk + kq * 8];
#pragma unroll
        for (int j = 0; j < 4; j++) {
            frag8 bw = *(const frag8*)&wb[(size_t)(s0 + j * 16 + lm) * 64 + kk + kq * 8];
            accE[j] = MFMA16(aq, bw, accE[j]);
        }
    }
    int m0 = w * 16 + kq * 4;
#pragma unroll
    for (int j = 0; j < 4; j++) {
        int s = s0 + j * 16 + lm;
        float beta = betaB[(size_t)s * H_ + head];
#pragma unroll
        for (int r = 0; r < 4; r++) {
            int t = t0 + m0 + r;
            Ez[(size_t)t * T_ + s] = f2bf((s <= t) ? -accE[j][r] * beta : 0.f);
        }
    }
}

// ---------------------------------------------------------------------------
// diag_inv: invert 64x64 unit-lower diag blocks of (I + L); Minv bf16 out.
// ---------------------------------------------------------------------------
__global__ void diag_inv(const ushort_t* __restrict__ Lb, ushort_t* __restrict__ Minv)
{
    int bi = blockIdx.x, z = blockIdx.y;
    const ushort_t* Lh = Lb + (size_t)z * TT_;
    __shared__ float Nb[64][65];
    __shared__ float Xc[64][65];
    int tid = threadIdx.x;
    for (int i = tid; i < 4096; i += 64) {
        int r = i >> 6, c = i & 63;
        Nb[r][c] = (c < r) ? bf2f(Lh[(size_t)(bi * 64 + r) * T_ + bi * 64 + c]) : 0.f;
    }
    __syncthreads();
    int j = tid;
    for (int t = 0; t < 64; t++) {
        float v = (t == j) ? 1.f : 0.f;
        for (int i = j; i < t; i++) v -= Nb[t][i] * Xc[i][j];
        Xc[t][j] = v;
    }
    __syncthreads();
    ushort_t* Mo = Minv + ((size_t)z * 16 + bi) * 4096;
    for (int i = tid; i < 4096; i += 64) Mo[i] = f2bf(Xc[i >> 6][i & 63]);
}

// ---------------------------------------------------------------------------
// solve_mfma: block-forward solve for one 64-col strip with LDS-staged
// L and C chunks. Grid (16, NH), block 256.
// ---------------------------------------------------------------------------
__global__ __launch_bounds__(256) void solve_mfma(
    ushort_t* __restrict__ Ct, const ushort_t* __restrict__ Lb,
    const ushort_t* __restrict__ Minv)
{
    int ct = blockIdx.x, z = blockIdx.y;
    ushort_t* Cz = Ct + (size_t)z * TT_;
    const ushort_t* Lz = Lb + (size_t)z * TT_;
    __shared__ ushort_t Cl[64][136];
    __shared__ ushort_t Ll[64][136];
    __shared__ ushort_t Xbt[64][72];
    int tid = threadIdx.x;
    int w = tid >> 6, l = tid & 63;
    int lm = l & 15, kq = l >> 4;
    int s0 = ct * 64;
    int m0 = w * 16 + kq * 4;
    for (int bi = ct; bi < 16; bi++) {
        f32x4 acc[4] = {};
        for (int kkc = s0; kkc < bi * 64; kkc += 128) {
            int len = bi * 64 - kkc; if (len > 128) len = 128;
            int lsh = (len == 128) ? 4 : 3;
            __syncthreads();
            for (int i = tid; i < (64 << lsh); i += 256) {
                int r = i >> lsh, c = (i & ((1 << lsh) - 1)) * 8;
                *(u16x8*)&Cl[r][c] = *(const u16x8*)&Cz[(size_t)(s0 + r) * T_ + kkc + c];
                *(u16x8*)&Ll[r][c] = *(const u16x8*)&Lz[(size_t)(bi * 64 + r) * T_ + kkc + c];
            }
            __syncthreads();
            for (int kk2 = 0; kk2 < len; kk2 += 32) {
                frag8 a = *(const frag8*)&Ll[w * 16 + lm][kk2 + kq * 8];
#pragma unroll
                for (int j = 0; j < 4; j++) {
                    frag8 b = *(const frag8*)&Cl[j * 16 + lm][kk2 + kq * 8];
                    acc[j] = MFMA16(a, b, acc[j]);
                }
            }
        }
        __syncthreads();
#pragma unroll
        for (int j = 0; j < 4; j++) {
            int sc = s0 + j * 16 + lm;
            u16x4 rhs = *(const u16x4*)&Cz[(size_t)sc * T_ + bi * 64 + m0];
            ushort_t xb[4];
#pragma unroll
            for (int r = 0; r < 4; r++) xb[r] = f2bf(bf2f(rhs[r]) - acc[j][r]);
            *(u16x4*)&Xbt[j * 16 + lm][m0] = *(u16x4*)xb;
        }
        __syncthreads();
        f32x4 res[4] = {};
        const ushort_t* Mo = Minv + ((size_t)z * 16 + bi) * 4096;
#pragma unroll
        for (int kk = 0; kk < 64; kk += 32) {
            frag8 a = *(const frag8*)&Mo[(size_t)(w * 16 + lm) * 64 + kk + kq * 8];
#pragma unroll
            for (int j = 0; j < 4; j++) {
                frag8 b = *(const frag8*)&Xbt[j * 16 + lm][kk + kq * 8];
                res[j] = MFMA16(a, b, res[j]);
            }
        }
#pragma unroll
        for (int j = 0; j < 4; j++) {
            int sc = s0 + j * 16 + lm;
            ushort_t cr[4];
#pragma unroll
            for (int r = 0; r < 4; r++) cr[r] = f2bf(res[j][r]);
            *(u16x4*)&Cz[(size_t)sc * T_ + bi * 64 + m0] = *(u16x4*)cr;
        }
        __syncthreads();
    }
}

// ---------------------------------------------------------------------------
// flash_split: one (s-tile, t-tile, head) per block; Em precomputed.
//   x = q.k^T + sum_k Em[t,k] C[k,s]; single-tile softmax partial -> Op/ml.
// Grid (16, 16, NH) with st>tb early-out. Block 256.
// Partial slots use triangular indexing: tri = tb*(tb+1)/2 + st, 136/head.
// ---------------------------------------------------------------------------
__global__ __launch_bounds__(256) void flash_split(
    const ushort_t* __restrict__ qh, const ushort_t* __restrict__ kh,
    const ushort_t* __restrict__ vt, const ushort_t* __restrict__ Em,
    const ushort_t* __restrict__ Ct, const float* __restrict__ Gb,
    ushort_t* __restrict__ Op, float* __restrict__ ml, int hs)
{
    int st = blockIdx.x, tb = blockIdx.y, z = blockIdx.z;
    if (st > tb) return;
    int t0 = tb * 64, s0 = st * 64;
    int head = hs + z;
    const ushort_t* qb = qh + (size_t)head * T_ * 64;
    const ushort_t* kb = kh + (size_t)head * T_ * 64;
    const ushort_t* vb = vt + (size_t)head * 64 * T_;
    const ushort_t* Ez = Em + (size_t)z * TT_;
    const ushort_t* Cz = Ct + (size_t)z * TT_;
    __shared__ ushort_t Kl[64][72];
    __shared__ ushort_t Vl[64][72];
    __shared__ ushort_t El[64][72];
    __shared__ ushort_t Cl[64][72];
    __shared__ ushort_t Pl[4][16][76];
    int tid = threadIdx.x;
    int w = tid >> 6, l = tid & 63;
    int lm = l & 15, kq = l >> 4;
    int rowA = t0 + w * 16 + lm;
    int m0 = w * 16 + kq * 4;
    for (int i = tid; i < 512; i += 256) {
        int r = i >> 3, c = (i & 7) * 8;
        *(u16x8*)&Kl[r][c] = *(const u16x8*)&kb[(size_t)(s0 + r) * 64 + c];
        *(u16x8*)&Vl[r][c] = *(const u16x8*)&vb[(size_t)r * T_ + s0 + c];
    }
    frag8 aq0 = *(const frag8*)&qb[(size_t)rowA * 64 + kq * 8];
    frag8 aq1 = *(const frag8*)&qb[(size_t)rowA * 64 + 32 + kq * 8];
    __syncthreads();
    f32x4 x[4] = {};
#pragma unroll
    for (int j = 0; j < 4; j++) {
        frag8 b0 = *(const frag8*)&Kl[j * 16 + lm][kq * 8];
        frag8 b1 = *(const frag8*)&Kl[j * 16 + lm][32 + kq * 8];
        x[j] = MFMA16(aq0, b0, x[j]);
        x[j] = MFMA16(aq1, b1, x[j]);
    }
    // correction: x += sum over k-chunks of Em(t,k) * C(k,s)
    for (int kc = s0; kc < t0 + 64; kc += 64) {
        __syncthreads();
        for (int i = tid; i < 512; i += 256) {
            int r = i >> 3, c = (i & 7) * 8;
            *(u16x8*)&El[r][c] = *(const u16x8*)&Ez[(size_t)(t0 + r) * T_ + kc + c];
            *(u16x8*)&Cl[r][c] = *(const u16x8*)&Cz[(size_t)(s0 + r) * T_ + kc + c];
        }
        __syncthreads();
#pragma unroll
        for (int kk2 = 0; kk2 < 64; kk2 += 32) {
            frag8 a = *(const frag8*)&El[w * 16 + lm][kk2 + kq * 8];
#pragma unroll
            for (int j = 0; j < 4; j++) {
                frag8 b = *(const frag8*)&Cl[j * 16 + lm][kk2 + kq * 8];
                x[j] = MFMA16(a, b, x[j]);
            }
        }
    }
    // single-tile softmax partial
    float lg[4][4];
#pragma unroll
    for (int j = 0; j < 4; j++) {
        int s = s0 + j * 16 + lm;
        float g = Gb[(size_t)s * H_ + head];
#pragma unroll
        for (int r = 0; r < 4; r++) {
            int t = t0 + m0 + r;
            lg[j][r] = (s <= t) ? (x[j][r] * 0.125f - g) : -1e30f;
        }
    }
    float mrow[4];
#pragma unroll
    for (int r = 0; r < 4; r++)
        mrow[r] = fmaxf(fmaxf(lg[0][r], lg[1][r]), fmaxf(lg[2][r], lg[3][r]));
#pragma unroll
    for (int d = 1; d < 16; d <<= 1)
#pragma unroll
        for (int r = 0; r < 4; r++) mrow[r] = fmaxf(mrow[r], __shfl_xor(mrow[r], d, 64));
    float lrow[4] = {0.f, 0.f, 0.f, 0.f};
#pragma unroll
    for (int j = 0; j < 4; j++)
#pragma unroll
        for (int r = 0; r < 4; r++) {
            float p = __expf(lg[j][r] - mrow[r]);
            lg[j][r] = p;
            lrow[r] += p;
        }
#pragma unroll
    for (int d = 1; d < 16; d <<= 1)
#pragma unroll
        for (int r = 0; r < 4; r++) lrow[r] += __shfl_xor(lrow[r], d, 64);
    // P -> per-wave slab (same-wave ordering), O = P @ V
#pragma unroll
    for (int j = 0; j < 4; j++)
#pragma unroll
        for (int r = 0; r < 4; r++)
            Pl[w][kq * 4 + r][j * 16 + lm] = f2bf(lg[j][r]);
    f32x4 o[4] = {};
#pragma unroll
    for (int j = 0; j < 4; j++) {
        frag8 b0 = *(const frag8*)&Vl[j * 16 + lm][kq * 8];
        frag8 b1 = *(const frag8*)&Vl[j * 16 + lm][32 + kq * 8];
        frag8 a0 = *(const frag8*)&Pl[w][lm][kq * 8];
        frag8 a1 = *(const frag8*)&Pl[w][lm][32 + kq * 8];
        o[j] = MFMA16(a0, b0, o[j]);
        o[j] = MFMA16(a1, b1, o[j]);
    }
    int tri = tb * (tb + 1) / 2 + st;
    size_t pbase = ((size_t)z * NTRI_ + tri) * 4096;
#pragma unroll
    for (int j = 0; j < 4; j++)
#pragma unroll
        for (int r = 0; r < 4; r++)
            Op[pbase + (size_t)(m0 + r) * 64 + j * 16 + lm] = f2bf(o[j][r]);
    if (lm == 0) {
        size_t mbase = ((size_t)z * NTRI_ + tri) * 128;
#pragma unroll
        for (int r = 0; r < 4; r++) {
            ml[mbase + m0 + r] = mrow[r];
            ml[mbase + 64 + m0 + r] = lrow[r];
        }
    }
}

// ---------------------------------------------------------------------------
// combine: merge <=16 partials per (t-tile, head) -> of bf16.
// ---------------------------------------------------------------------------
__global__ __launch_bounds__(256) void combine(
    const ushort_t* __restrict__ Op, const float* __restrict__ ml,
    ushort_t* __restrict__ of, int hs)
{
    int tb = blockIdx.x, z = blockIdx.y;
    int head = hs + z;
    int tid = threadIdx.x;
    int row = tid >> 2, cg = (tid & 3) * 16;
    size_t pb0 = (size_t)z * NTRI_ + (size_t)tb * (tb + 1) / 2;
    float M = -1e30f;
    for (int st = 0; st <= tb; st++)
        M = fmaxf(M, ml[(pb0 + st) * 128 + row]);
    float acc[16] = {};
    float lsum = 0.f;
    for (int st = 0; st <= tb; st++) {
        float mp = ml[(pb0 + st) * 128 + row];
        float lp = ml[(pb0 + st) * 128 + 64 + row];
        float sc = __expf(mp - M);
        lsum += lp * sc;
        const ushort_t* op = Op + (pb0 + st) * 4096 + (size_t)row * 64 + cg;
#pragma unroll
        for (int i = 0; i < 16; i++) acc[i] += bf2f(op[i]) * sc;
    }
    float inv = 1.f / lsum;
    int t = tb * 64 + row;
    ushort_t* dst = of + (size_t)t * D_ + (size_t)head * 64 + cg;
#pragma unroll
    for (int i = 0; i < 16; i++) dst[i] = f2bf(acc[i] * inv);
}

// ---------------------------------------------------------------------------
extern "C" void kernel_launch(void* const* d_in, const int* in_sizes, int n_in,
                              void* d_out, int out_size, void* d_ws, size_t ws_size,
                              hipStream_t stream)
{
    const float* h     = (const float*)d_in[0];
    const float* Wq    = (const float*)d_in[1];
    const float* Wk    = (const float*)d_in[2];
    const float* Wv    = (const float*)d_in[3];
    const float* Ww1   = (const float*)d_in[4];
    const float* Ww2   = (const float*)d_in[5];
    const float* convw = (const float*)d_in[6];
    const float* Wbt   = (const float*)d_in[7];
    const float* bbt   = (const float*)d_in[8];
    const float* Wg    = (const float*)d_in[9];
    const float* bgp   = (const float*)d_in[10];
    const float* Wo    = (const float*)d_in[11];
    float* out = (float*)d_out;

    float* ws = (float*)d_ws;
    size_t off = 0;
    auto allocF = [&](size_t nf) { float* p = ws + off; off += (nf + 1023) & ~(size_t)1023; return p; };

    // ---- persistent region (lives across the whole launch) ----
    float*    betaB = allocF((size_t)T_ * H_);
    float*    Gb    = allocF((size_t)T_ * H_);
    ushort_t* h_bf  = (ushort_t*)allocF(TD_ / 2);   // reused as of_bf after QKV GEMM
    ushort_t* of_bf = h_bf;
    ushort_t* w1bf  = (ushort_t*)allocF((size_t)T_ * 32 / 2);
    ushort_t* Ww2t  = (ushort_t*)allocF((size_t)D_ * 32 / 2);
    ushort_t* qkv   = (ushort_t*)allocF((size_t)3 * TD_ / 2);
    ushort_t* qh    = qkv;
    ushort_t* kh    = qkv + TD_;
    ushort_t* vt    = qkv + 2 * TD_;
    ushort_t* wh    = (ushort_t*)allocF(TD_ / 2);

    size_t scrOff = off;            // start of the overlaid scratch region
    size_t capF = ws_size / 4;

    // ---- phase A scratch (projection prep; dead before the chunk loop) ----
    float*    wr  = allocF(TD_);
    float*    s96 = allocF((size_t)T_ * 128);
    ushort_t* Wtc = (ushort_t*)allocF((size_t)6272 * D_ / 2);   // QKV + 96-pack

    // ---- phase B scratch overlays phase A (per-head chunk buffers) ----
    // perHead: ELb (L then Em) + Ct (TT_ bf16 each) + triangular Op + Mv + ml
    int NH = 32;
    ushort_t *ELb, *Ct, *OpB, *Mv;
    float* mlB;
    for (;;) {
        off = scrOff;
        ELb = (ushort_t*)allocF((size_t)NH * TT_ / 2);            // L, then Em
        Ct  = (ushort_t*)allocF((size_t)NH * TT_ / 2);
        OpB = (ushort_t*)allocF((size_t)NH * NTRI_ * 4096 / 2);   // triangular partials
        Mv  = (ushort_t*)allocF((size_t)NH * 16 * 4096 / 2);
        mlB = allocF((size_t)NH * NTRI_ * 128);
        if (off <= capF || NH == 1) break;
        NH >>= 1;
    }

    // ---- phase C scratch: Wo^T overlays phase B (all per-head dead) ----
    ushort_t* WoT = (ushort_t*)(ws + scrOff);

    dim3 blk(256);
    dim3 tcvB(32, 8);
    dim3 tcvG(D_ / 32, D_ / 32);

    // fused QKV + 96-proj via one MFMA GEMM (N = 6272)
    convert_bf16<<<dim3((TD_ + 255) / 256), blk, 0, stream>>>(h, h_bf, (int)TD_);
    transpose_convert<<<tcvG, tcvB, 0, stream>>>(Wq, Wtc, D_, D_);
    transpose_convert<<<tcvG, tcvB, 0, stream>>>(Wk, Wtc + (size_t)D_ * D_, D_, D_);
    transpose_convert<<<tcvG, tcvB, 0, stream>>>(Wv, Wtc + (size_t)2 * D_ * D_, D_, D_);
    pack96<<<dim3(128, 8), blk, 0, stream>>>(Ww1, Wbt, Wg, Wtc + (size_t)3 * D_ * D_);
    mfma_gemm<3><<<dim3(6272 / 128, T_ / 128), blk, 0, stream>>>(
        h_bf, Wtc, qkv, s96, T_, 6272, D_);

    // gates + w path
    bg96<<<dim3(T_ * 128 / 256), blk, 0, stream>>>(s96, bbt, bgp, w1bf, betaB, Gb);
    scan_g<<<dim3(H_), blk, 0, stream>>>(Gb);
    transpose_convert<<<dim3(D_ / 32, 1), tcvB, 0, stream>>>(Ww2, Ww2t, 32, D_);
    mfma_gemm<0><<<dim3(D_ / 128, T_ / 128), blk, 0, stream>>>(
        w1bf, Ww2t, wr, nullptr, T_, D_, 32);
    conv_silu_norm<<<dim3(T_ * H_), dim3(64), 0, stream>>>(wr, convw, wh);

    int nChunks = H_ / NH;
    for (int c = 0; c < nChunks; c++) {
        int hs = c * NH;
        pairdotLC<<<dim3(16, 16, NH), blk, 0, stream>>>(kh, wh, betaB, ELb, Ct, hs);
        diag_inv<<<dim3(16, NH), dim3(64), 0, stream>>>(ELb, Mv);
        solve_mfma<<<dim3(16, NH), blk, 0, stream>>>(Ct, ELb, Mv);
        pairdotE<<<dim3(16, 16, NH), blk, 0, stream>>>(qh, wh, betaB, ELb, hs);
        flash_split<<<dim3(16, 16, NH), blk, 0, stream>>>(
            qh, kh, vt, ELb, Ct, Gb, OpB, mlB, hs);
        combine<<<dim3(16, NH), blk, 0, stream>>>(OpB, mlB, of_bf, hs);
    }

    // out = of @ Wo via MFMA
    transpose_convert<<<tcvG, tcvB, 0, stream>>>(Wo, WoT, D_, D_);
    mfma_gemm<0><<<dim3(D_ / 128, T_ / 128), blk, 0, stream>>>(
        of_bf, WoT, out, nullptr, T_, D_, D_);
}

// Round 2
// 837.885 us; speedup vs baseline: 1.0557x; 1.0557x over previous
//
#include <hip/hip_runtime.h>
#include <hip/hip_bf16.h>

typedef __hip_bfloat16 bf16;
typedef unsigned short ushort_t;

#define T_  1024
#define D_  2048
#define H_  32
#define HD_ 64
#define NTRI_ 136   // 16*17/2 lower-triangular tile pairs

static const size_t TT_ = (size_t)T_ * T_;
static const size_t TD_ = (size_t)T_ * D_;

__device__ __forceinline__ ushort_t f2bf(float v) {
    bf16 b = __float2bfloat16(v);
    return *(ushort_t*)&b;
}
__device__ __forceinline__ float bf2f(ushort_t u) {
    bf16 b = *(bf16*)&u;
    return __bfloat162float(b);
}

typedef __attribute__((ext_vector_type(8))) short frag8;
typedef __attribute__((ext_vector_type(4))) float f32x4;
typedef __attribute__((ext_vector_type(4))) unsigned short u16x4;
typedef __attribute__((ext_vector_type(8))) unsigned short u16x8;

#define MFMA16(a, b, c) __builtin_amdgcn_mfma_f32_16x16x32_bf16((a), (b), (c), 0, 0, 0)

// ---------------------------------------------------------------------------
// MFMA GEMM: C = A[M,K]bf16 @ Bt[N,K]^T. 128x128 tile, BK=32.
// OUT: 0 = f32 row-major [M,N]
//      3 = packed QKV+small: col<2048 -> qh head-major bf16; <4096 -> kh;
//          <6144 -> vt transposed [head][64][T]; >=6144 -> Cout2 f32 [M][128]
// ---------------------------------------------------------------------------
template <int OUT>
__global__ __launch_bounds__(256) void mfma_gemm(
    const ushort_t* __restrict__ A, const ushort_t* __restrict__ Bt,
    void* __restrict__ Cout, void* __restrict__ Cout2, int M, int N, int K)
{
    __shared__ short Al[128 * 32];
    __shared__ short Bl[128 * 32];
    int tid = threadIdx.x;
    int w = tid >> 6, l = tid & 63;
    int row0 = blockIdx.y * 128, col0 = blockIdx.x * 128;
    int mq = (w >> 1) * 64, nq = (w & 1) * 64;
    int lm = l & 15, kq = l >> 4;
    f32x4 acc[4][4] = {};
    const ushort_t* Ap = A + (size_t)row0 * K;
    const ushort_t* Bp = Bt + (size_t)col0 * K;
    for (int kk = 0; kk < K; kk += 32) {
        __syncthreads();
#pragma unroll
        for (int r = 0; r < 2; r++) {
            int c = r * 256 + w * 64 + l;
            int row = c >> 2, kc = (c & 3) * 8;
            const ushort_t* ga = Ap + (size_t)row * K + kk + kc;
            const ushort_t* gb = Bp + (size_t)row * K + kk + kc;
            short* la = Al + (size_t)(r * 256 + w * 64) * 8;
            short* lb = Bl + (size_t)(r * 256 + w * 64) * 8;
            __builtin_amdgcn_global_load_lds((const __attribute__((address_space(1))) void*)ga,
                                             (__attribute__((address_space(3))) void*)la, 16, 0, 0);
            __builtin_amdgcn_global_load_lds((const __attribute__((address_space(1))) void*)gb,
                                             (__attribute__((address_space(3))) void*)lb, 16, 0, 0);
        }
        __builtin_amdgcn_s_waitcnt(0);
        __syncthreads();
        frag8 af[4], bfg[4];
#pragma unroll
        for (int i = 0; i < 4; i++)
            af[i] = *(const frag8*)&Al[(size_t)(mq + i * 16 + lm) * 32 + kq * 8];
#pragma unroll
        for (int j = 0; j < 4; j++)
            bfg[j] = *(const frag8*)&Bl[(size_t)(nq + j * 16 + lm) * 32 + kq * 8];
#pragma unroll
        for (int i = 0; i < 4; i++)
#pragma unroll
            for (int j = 0; j < 4; j++)
                acc[i][j] = MFMA16(af[i], bfg[j], acc[i][j]);
    }
#pragma unroll
    for (int i = 0; i < 4; i++)
#pragma unroll
        for (int j = 0; j < 4; j++)
#pragma unroll
            for (int r = 0; r < 4; r++) {
                int row = row0 + mq + i * 16 + kq * 4 + r;
                int col = col0 + nq + j * 16 + lm;
                float v = acc[i][j][r];
                if (OUT == 0) {
                    ((float*)Cout)[(size_t)row * N + col] = v;
                } else {
                    ushort_t* q = (ushort_t*)Cout;
                    int which = col >> 11, cl = col & 2047;
                    int hd = cl >> 6, d = cl & 63;
                    if (which == 0)
                        q[((size_t)hd * M + row) * 64 + d] = f2bf(v);
                    else if (which == 1)
                        q[(size_t)M * 2048 + ((size_t)hd * M + row) * 64 + d] = f2bf(v);
                    else if (which == 2)
                        q[(size_t)M * 4096 + ((size_t)hd * 64 + d) * M + row] = f2bf(v);
                    else
                        ((float*)Cout2)[(size_t)row * 128 + (col - 6144)] = v;
                }
            }
}

// ---------------------------------------------------------------------------
__global__ void transpose_convert(const float* __restrict__ W, ushort_t* __restrict__ Wt,
                                  int R, int Cc)
{
    __shared__ float tile[32][33];
    int bx = blockIdx.x * 32, by = blockIdx.y * 32;
    int tx = threadIdx.x, ty = threadIdx.y;
    for (int i = ty; i < 32; i += 8)
        tile[i][tx] = W[(size_t)(by + i) * Cc + bx + tx];
    __syncthreads();
    for (int i = ty; i < 32; i += 8)
        Wt[(size_t)(bx + i) * R + by + tx] = f2bf(tile[tx][i]);
}

// pack Ww1^T/Wbt^T/Wg^T (+zero pad) into rows [0..128) of dst[128][2048]
__global__ void pack96(const float* __restrict__ Ww1, const float* __restrict__ Wbt,
                       const float* __restrict__ Wg, ushort_t* __restrict__ dst)
{
    int r = blockIdx.x;
    int k = blockIdx.y * 256 + threadIdx.x;
    float v = 0.f;
    if (r < 32)       v = Ww1[(size_t)k * 32 + r];
    else if (r < 64)  v = Wbt[(size_t)k * 32 + (r - 32)];
    else if (r < 96)  v = Wg[(size_t)k * 32 + (r - 64)];
    dst[(size_t)r * 2048 + k] = f2bf(v);
}

__global__ void convert_bf16(const float* __restrict__ in, ushort_t* __restrict__ out, int n)
{
    int i = blockIdx.x * 256 + threadIdx.x;
    if (i < n) out[i] = f2bf(in[i]);
}

// epilogue of the 96-proj: w1 bf16, beta, G(pre-scan)
__global__ void bg96(const float* __restrict__ s96, const float* __restrict__ bbt,
                     const float* __restrict__ bgp, ushort_t* __restrict__ w1bf,
                     float* __restrict__ betaB, float* __restrict__ Gb)
{
    int idx = blockIdx.x * 256 + threadIdx.x;   // over T_*128
    int t = idx >> 7, o = idx & 127;
    if (o >= 96) return;
    float v = s96[(size_t)t * 128 + o];
    if (o < 32) {
        w1bf[(size_t)t * 32 + o] = f2bf(v);
    } else if (o < 64) {
        float xb = v + bbt[o - 32];
        betaB[(size_t)t * H_ + (o - 32)] = 2.f / (1.f + expf(-xb));
    } else {
        float xg = v + bgp[o - 64];
        Gb[(size_t)t * H_ + (o - 64)] =
            (xg >= 0.f) ? -log1pf(expf(-xg)) : (xg - log1pf(expf(xg)));
    }
}

// parallel inclusive scan of G[:, h] per head. Grid (H_), block 256.
__global__ void scan_g(float* __restrict__ G)
{
    int h = blockIdx.x;
    int tid = threadIdx.x;
    __shared__ float psum[256];
    float v[4];
    float s = 0.f;
#pragma unroll
    for (int r = 0; r < 4; r++) {
        v[r] = G[(size_t)(tid * 4 + r) * H_ + h];
        s += v[r];
    }
    psum[tid] = s;
    __syncthreads();
    for (int off = 1; off < 256; off <<= 1) {
        float t = (tid >= off) ? psum[tid - off] : 0.f;
        __syncthreads();
        psum[tid] += t;
        __syncthreads();
    }
    float run = (tid > 0) ? psum[tid - 1] : 0.f;
#pragma unroll
    for (int r = 0; r < 4; r++) {
        run += v[r];
        G[(size_t)(tid * 4 + r) * H_ + h] = run;
    }
}

// conv(3) + silu + l2norm -> wh bf16 head-major [H][T][64]
__global__ void conv_silu_norm(const float* __restrict__ wr, const float* __restrict__ convw,
                               ushort_t* __restrict__ wh)
{
    int b = blockIdx.x;
    int t = b >> 5, h = b & 31;
    int d = threadIdx.x;
    int c = h * 64 + d;
    float c0 = convw[c * 3 + 0];
    float c1 = convw[c * 3 + 1];
    float c2 = convw[c * 3 + 2];
    float x = c2 * wr[(size_t)t * D_ + c];
    if (t >= 1) x += c1 * wr[(size_t)(t - 1) * D_ + c];
    if (t >= 2) x += c0 * wr[(size_t)(t - 2) * D_ + c];
    float y = x / (1.f + expf(-x));
    float ss = y * y;
    for (int off = 32; off > 0; off >>= 1) ss += __shfl_xor(ss, off, 64);
    wh[((size_t)h * T_ + t) * 64 + d] = f2bf(y * rsqrtf(ss));
}

// ---------------------------------------------------------------------------
// pairdotLC: per lower tile (t0,s0):
//   L[t][s]  = strict(w_t.w_s)*beta[s]   (bf16 row-major, into ELb)
//   Ct[s][t] = strict(w_t.k_s)           (bf16 TRANSPOSED [s][t])
// ---------------------------------------------------------------------------
__global__ __launch_bounds__(256) void pairdotLC(
    const ushort_t* __restrict__ kh, const ushort_t* __restrict__ wh,
    const float* __restrict__ betaB,
    ushort_t* __restrict__ ELb, ushort_t* __restrict__ Ct, int hs)
{
    int s0 = blockIdx.x * 64, t0 = blockIdx.y * 64, z = blockIdx.z;
    if (s0 > t0) return;
    int head = hs + z;
    const ushort_t* kb = kh + (size_t)head * T_ * 64;
    const ushort_t* wb = wh + (size_t)head * T_ * 64;
    ushort_t* Lz = ELb + (size_t)z * TT_;
    ushort_t* Cz = Ct + (size_t)z * TT_;
    int tid = threadIdx.x;
    int w = tid >> 6, l = tid & 63;
    int lm = l & 15, kq = l >> 4;
    int rowA = t0 + w * 16 + lm;
    f32x4 accL[4] = {}, accS[4] = {};
#pragma unroll
    for (int kk = 0; kk < 64; kk += 32) {
        frag8 aw = *(const frag8*)&wb[(size_t)rowA * 64 + kk + kq * 8];
#pragma unroll
        for (int j = 0; j < 4; j++) {
            int colr = s0 + j * 16 + lm;
            frag8 bw = *(const frag8*)&wb[(size_t)colr * 64 + kk + kq * 8];
            frag8 bk = *(const frag8*)&kb[(size_t)colr * 64 + kk + kq * 8];
            accL[j] = MFMA16(aw, bw, accL[j]);
            accS[j] = MFMA16(aw, bk, accS[j]);
        }
    }
    int m0 = w * 16 + kq * 4;
#pragma unroll
    for (int j = 0; j < 4; j++) {
        int s = s0 + j * 16 + lm;
        float beta = betaB[(size_t)s * H_ + head];
        ushort_t cl[4];
#pragma unroll
        for (int r = 0; r < 4; r++) {
            int t = t0 + m0 + r;
            Lz[(size_t)t * T_ + s] = f2bf((s < t) ? accL[j][r] * beta : 0.f);
            cl[r] = f2bf((s < t) ? accS[j][r] : 0.f);
        }
        *(u16x4*)&Cz[(size_t)s * T_ + t0 + m0] = *(u16x4*)cl;
    }
}

// pairdotE: Em[t][s] = -causal(q_t.w_s)*beta[s] into ELb (L dead post-solve)
__global__ __launch_bounds__(256) void pairdotE(
    const ushort_t* __restrict__ qh, const ushort_t* __restrict__ wh,
    const float* __restrict__ betaB, ushort_t* __restrict__ ELb, int hs)
{
    int s0 = blockIdx.x * 64, t0 = blockIdx.y * 64, z = blockIdx.z;
    if (s0 > t0) return;
    int head = hs + z;
    const ushort_t* qb = qh + (size_t)head * T_ * 64;
    const ushort_t* wb = wh + (size_t)head * T_ * 64;
    ushort_t* Ez = ELb + (size_t)z * TT_;
    int tid = threadIdx.x;
    int w = tid >> 6, l = tid & 63;
    int lm = l & 15, kq = l >> 4;
    int rowA = t0 + w * 16 + lm;
    f32x4 accE[4] = {};
#pragma unroll
    for (int kk = 0; kk < 64; kk += 32) {
        frag8 aq = *(const frag8*)&qb[(size_t)rowA * 64 + kk + kq * 8];
#pragma unroll
        for (int j = 0; j < 4; j++) {
            frag8 bw = *(const frag8*)&wb[(size_t)(s0 + j * 16 + lm) * 64 + kk + kq * 8];
            accE[j] = MFMA16(aq, bw, accE[j]);
        }
    }
    int m0 = w * 16 + kq * 4;
#pragma unroll
    for (int j = 0; j < 4; j++) {
        int s = s0 + j * 16 + lm;
        float beta = betaB[(size_t)s * H_ + head];
#pragma unroll
        for (int r = 0; r < 4; r++) {
            int t = t0 + m0 + r;
            Ez[(size_t)t * T_ + s] = f2bf((s <= t) ? -accE[j][r] * beta : 0.f);
        }
    }
}

// ---------------------------------------------------------------------------
// diag_inv: invert 64x64 unit-lower diag blocks of (I + L); Minv bf16 out.
// ---------------------------------------------------------------------------
__global__ void diag_inv(const ushort_t* __restrict__ Lb, ushort_t* __restrict__ Minv)
{
    int bi = blockIdx.x, z = blockIdx.y;
    const ushort_t* Lh = Lb + (size_t)z * TT_;
    __shared__ float Nb[64][65];
    __shared__ float Xc[64][65];
    int tid = threadIdx.x;
    for (int i = tid; i < 4096; i += 64) {
        int r = i >> 6, c = i & 63;
        Nb[r][c] = (c < r) ? bf2f(Lh[(size_t)(bi * 64 + r) * T_ + bi * 64 + c]) : 0.f;
    }
    __syncthreads();
    int j = tid;
    for (int t = 0; t < 64; t++) {
        float v = (t == j) ? 1.f : 0.f;
        for (int i = j; i < t; i++) v -= Nb[t][i] * Xc[i][j];
        Xc[t][j] = v;
    }
    __syncthreads();
    ushort_t* Mo = Minv + ((size_t)z * 16 + bi) * 4096;
    for (int i = tid; i < 4096; i += 64) Mo[i] = f2bf(Xc[i >> 6][i & 63]);
}

// ---------------------------------------------------------------------------
// solve_mfma: block-forward solve for one 64-col strip.
// Latency-pipelined: register-batched staging (all loads issued before any
// LDS write), 1-chunk-ahead register prefetch (A/B sets), cross-step chunk0
// prefetch during the Minv-apply epilogue, and step-static Minv/rhs loads
// hoisted to step start. Grid (16, NH), block 256.
// ---------------------------------------------------------------------------
__global__ __launch_bounds__(256) void solve_mfma(
    ushort_t* __restrict__ Ct, const ushort_t* __restrict__ Lb,
    const ushort_t* __restrict__ Minv)
{
    int ct = blockIdx.x, z = blockIdx.y;
    ushort_t* Cz = Ct + (size_t)z * TT_;
    const ushort_t* Lz = Lb + (size_t)z * TT_;
    __shared__ ushort_t Cl[64][136];
    __shared__ ushort_t Ll[64][136];
    __shared__ ushort_t Xbt[64][72];
    int tid = threadIdx.x;
    int w = tid >> 6, l = tid & 63;
    int lm = l & 15, kq = l >> 4;
    int s0 = ct * 64;
    int m0 = w * 16 + kq * 4;

    u16x8 cA[4], lA[4], cB[4], lB[4];

    // issue all chunk loads back-to-back into regs (no intervening waits)
    auto issue = [&](u16x8 (&rc)[4], u16x8 (&rl)[4], int kkc, int lrow, int lsh) {
#pragma unroll
        for (int t = 0; t < 4; t++) {
            int i = tid + t * 256;
            if (i < (64 << lsh)) {
                int r = i >> lsh, c = (i & ((1 << lsh) - 1)) * 8;
                rc[t] = *(const u16x8*)&Cz[(size_t)(s0 + r) * T_ + kkc + c];
                rl[t] = *(const u16x8*)&Lz[(size_t)(lrow + r) * T_ + kkc + c];
            }
        }
    };
    auto stage = [&](u16x8 (&rc)[4], u16x8 (&rl)[4], int lsh) {
#pragma unroll
        for (int t = 0; t < 4; t++) {
            int i = tid + t * 256;
            if (i < (64 << lsh)) {
                int r = i >> lsh, c = (i & ((1 << lsh) - 1)) * 8;
                *(u16x8*)&Cl[r][c] = rc[t];
                *(u16x8*)&Ll[r][c] = rl[t];
            }
        }
    };
    auto compute = [&](int len, f32x4 (&acc)[4]) {
        for (int kk2 = 0; kk2 < len; kk2 += 32) {
            frag8 a = *(const frag8*)&Ll[w * 16 + lm][kk2 + kq * 8];
#pragma unroll
            for (int j = 0; j < 4; j++) {
                frag8 b = *(const frag8*)&Cl[j * 16 + lm][kk2 + kq * 8];
                acc[j] = MFMA16(a, b, acc[j]);
            }
        }
    };

    bool pre0 = false;
    for (int bi = ct; bi < 16; bi++) {
        int kend = bi * 64;   // also the L block-row base for this step
        // step-static loads hoisted: latency hides under the chunk loop
        const ushort_t* Mo = Minv + ((size_t)z * 16 + bi) * 4096;
        frag8 ma0 = *(const frag8*)&Mo[(size_t)(w * 16 + lm) * 64 + kq * 8];
        frag8 ma1 = *(const frag8*)&Mo[(size_t)(w * 16 + lm) * 64 + 32 + kq * 8];
        u16x4 rhs[4];
#pragma unroll
        for (int j = 0; j < 4; j++)
            rhs[j] = *(const u16x4*)&Cz[(size_t)(s0 + j * 16 + lm) * T_ + kend + m0];

        f32x4 acc[4] = {};
        int kkc = s0;
        bool haveA = pre0;
        while (kkc < kend) {
            int len = kend - kkc; if (len > 128) len = 128;
            int lsh = (len == 128) ? 4 : 3;
            __syncthreads();                       // LDS free + prior stores drained
            if (!haveA) issue(cA, lA, kkc, kend, lsh);
            stage(cA, lA, lsh);
            bool nb = (kkc + 128 < kend);
            if (nb) {
                int len2 = kend - kkc - 128; if (len2 > 128) len2 = 128;
                issue(cB, lB, kkc + 128, kend, (len2 == 128) ? 4 : 3);
            }
            __syncthreads();
            compute(len, acc);
            kkc += 128;
            if (!nb) break;

            len = kend - kkc; if (len > 128) len = 128;
            lsh = (len == 128) ? 4 : 3;
            __syncthreads();
            stage(cB, lB, lsh);
            bool na = (kkc + 128 < kend);
            if (na) {
                int len2 = kend - kkc - 128; if (len2 > 128) len2 = 128;
                issue(cA, lA, kkc + 128, kend, (len2 == 128) ? 4 : 3);
            }
            __syncthreads();
            compute(len, acc);
            kkc += 128;
            haveA = na;
            if (!na) break;
        }

        // epilogue: X = rhs - acc, then res = Minv_diag @ X
#pragma unroll
        for (int j = 0; j < 4; j++) {
            ushort_t xb[4];
#pragma unroll
            for (int r = 0; r < 4; r++) xb[r] = f2bf(bf2f(rhs[j][r]) - acc[j][r]);
            *(u16x4*)&Xbt[j * 16 + lm][m0] = *(u16x4*)xb;
        }
        __syncthreads();
        // cross-step prefetch of next step's chunk0 (cols [s0,s0+128) were
        // solved >=2 steps ago when bi-ct>=2, so no dependency on this store)
        pre0 = (bi + 1 < 16) && (bi - ct >= 2);
        if (pre0) issue(cA, lA, s0, (bi + 1) * 64, 4);
        f32x4 res[4] = {};
#pragma unroll
        for (int j = 0; j < 4; j++) {
            frag8 b0 = *(const frag8*)&Xbt[j * 16 + lm][kq * 8];
            frag8 b1 = *(const frag8*)&Xbt[j * 16 + lm][32 + kq * 8];
            res[j] = MFMA16(ma0, b0, res[j]);
            res[j] = MFMA16(ma1, b1, res[j]);
        }
#pragma unroll
        for (int j = 0; j < 4; j++) {
            int sc = s0 + j * 16 + lm;
            ushort_t cr[4];
#pragma unroll
            for (int r = 0; r < 4; r++) cr[r] = f2bf(res[j][r]);
            *(u16x4*)&Cz[(size_t)sc * T_ + kend + m0] = *(u16x4*)cr;
        }
    }
}

// ---------------------------------------------------------------------------
// flash_split: one (s-tile, t-tile, head) per block; Em precomputed.
//   x = q.k^T + sum_k Em[t,k] C[k,s]; single-tile softmax partial -> Op/ml.
// Grid (16, 16, NH) with st>tb early-out. Block 256.
// Partial slots use triangular indexing: tri = tb*(tb+1)/2 + st, 136/head.
// ---------------------------------------------------------------------------
__global__ __launch_bounds__(256) void flash_split(
    const ushort_t* __restrict__ qh, const ushort_t* __restrict__ kh,
    const ushort_t* __restrict__ vt, const ushort_t* __restrict__ Em,
    const ushort_t* __restrict__ Ct, const float* __restrict__ Gb,
    ushort_t* __restrict__ Op, float* __restrict__ ml, int hs)
{
    int st = blockIdx.x, tb = blockIdx.y, z = blockIdx.z;
    if (st > tb) return;
    int t0 = tb * 64, s0 = st * 64;
    int head = hs + z;
    const ushort_t* qb = qh + (size_t)head * T_ * 64;
    const ushort_t* kb = kh + (size_t)head * T_ * 64;
    const ushort_t* vb = vt + (size_t)head * 64 * T_;
    const ushort_t* Ez = Em + (size_t)z * TT_;
    const ushort_t* Cz = Ct + (size_t)z * TT_;
    __shared__ ushort_t Kl[64][72];
    __shared__ ushort_t Vl[64][72];
    __shared__ ushort_t El[64][72];
    __shared__ ushort_t Cl[64][72];
    __shared__ ushort_t Pl[4][16][76];
    int tid = threadIdx.x;
    int w = tid >> 6, l = tid & 63;
    int lm = l & 15, kq = l >> 4;
    int rowA = t0 + w * 16 + lm;
    int m0 = w * 16 + kq * 4;
    for (int i = tid; i < 512; i += 256) {
        int r = i >> 3, c = (i & 7) * 8;
        *(u16x8*)&Kl[r][c] = *(const u16x8*)&kb[(size_t)(s0 + r) * 64 + c];
        *(u16x8*)&Vl[r][c] = *(const u16x8*)&vb[(size_t)r * T_ + s0 + c];
    }
    frag8 aq0 = *(const frag8*)&qb[(size_t)rowA * 64 + kq * 8];
    frag8 aq1 = *(const frag8*)&qb[(size_t)rowA * 64 + 32 + kq * 8];
    __syncthreads();
    f32x4 x[4] = {};
#pragma unroll
    for (int j = 0; j < 4; j++) {
        frag8 b0 = *(const frag8*)&Kl[j * 16 + lm][kq * 8];
        frag8 b1 = *(const frag8*)&Kl[j * 16 + lm][32 + kq * 8];
        x[j] = MFMA16(aq0, b0, x[j]);
        x[j] = MFMA16(aq1, b1, x[j]);
    }
    // correction: x += sum over k-chunks of Em(t,k) * C(k,s)
    for (int kc = s0; kc < t0 + 64; kc += 64) {
        __syncthreads();
        for (int i = tid; i < 512; i += 256) {
            int r = i >> 3, c = (i & 7) * 8;
            *(u16x8*)&El[r][c] = *(const u16x8*)&Ez[(size_t)(t0 + r) * T_ + kc + c];
            *(u16x8*)&Cl[r][c] = *(const u16x8*)&Cz[(size_t)(s0 + r) * T_ + kc + c];
        }
        __syncthreads();
#pragma unroll
        for (int kk2 = 0; kk2 < 64; kk2 += 32) {
            frag8 a = *(const frag8*)&El[w * 16 + lm][kk2 + kq * 8];
#pragma unroll
            for (int j = 0; j < 4; j++) {
                frag8 b = *(const frag8*)&Cl[j * 16 + lm][kk2 + kq * 8];
                x[j] = MFMA16(a, b, x[j]);
            }
        }
    }
    // single-tile softmax partial
    float lg[4][4];
#pragma unroll
    for (int j = 0; j < 4; j++) {
        int s = s0 + j * 16 + lm;
        float g = Gb[(size_t)s * H_ + head];
#pragma unroll
        for (int r = 0; r < 4; r++) {
            int t = t0 + m0 + r;
            lg[j][r] = (s <= t) ? (x[j][r] * 0.125f - g) : -1e30f;
        }
    }
    float mrow[4];
#pragma unroll
    for (int r = 0; r < 4; r++)
        mrow[r] = fmaxf(fmaxf(lg[0][r], lg[1][r]), fmaxf(lg[2][r], lg[3][r]));
#pragma unroll
    for (int d = 1; d < 16; d <<= 1)
#pragma unroll
        for (int r = 0; r < 4; r++) mrow[r] = fmaxf(mrow[r], __shfl_xor(mrow[r], d, 64));
    float lrow[4] = {0.f, 0.f, 0.f, 0.f};
#pragma unroll
    for (int j = 0; j < 4; j++)
#pragma unroll
        for (int r = 0; r < 4; r++) {
            float p = __expf(lg[j][r] - mrow[r]);
            lg[j][r] = p;
            lrow[r] += p;
        }
#pragma unroll
    for (int d = 1; d < 16; d <<= 1)
#pragma unroll
        for (int r = 0; r < 4; r++) lrow[r] += __shfl_xor(lrow[r], d, 64);
    // P -> per-wave slab (same-wave ordering), O = P @ V
#pragma unroll
    for (int j = 0; j < 4; j++)
#pragma unroll
        for (int r = 0; r < 4; r++)
            Pl[w][kq * 4 + r][j * 16 + lm] = f2bf(lg[j][r]);
    f32x4 o[4] = {};
#pragma unroll
    for (int j = 0; j < 4; j++) {
        frag8 b0 = *(const frag8*)&Vl[j * 16 + lm][kq * 8];
        frag8 b1 = *(const frag8*)&Vl[j * 16 + lm][32 + kq * 8];
        frag8 a0 = *(const frag8*)&Pl[w][lm][kq * 8];
        frag8 a1 = *(const frag8*)&Pl[w][lm][32 + kq * 8];
        o[j] = MFMA16(a0, b0, o[j]);
        o[j] = MFMA16(a1, b1, o[j]);
    }
    int tri = tb * (tb + 1) / 2 + st;
    size_t pbase = ((size_t)z * NTRI_ + tri) * 4096;
#pragma unroll
    for (int j = 0; j < 4; j++)
#pragma unroll
        for (int r = 0; r < 4; r++)
            Op[pbase + (size_t)(m0 + r) * 64 + j * 16 + lm] = f2bf(o[j][r]);
    if (lm == 0) {
        size_t mbase = ((size_t)z * NTRI_ + tri) * 128;
#pragma unroll
        for (int r = 0; r < 4; r++) {
            ml[mbase + m0 + r] = mrow[r];
            ml[mbase + 64 + m0 + r] = lrow[r];
        }
    }
}

// ---------------------------------------------------------------------------
// combine: merge <=16 partials per (t-tile, head) -> of bf16.
// ---------------------------------------------------------------------------
__global__ __launch_bounds__(256) void combine(
    const ushort_t* __restrict__ Op, const float* __restrict__ ml,
    ushort_t* __restrict__ of, int hs)
{
    int tb = blockIdx.x, z = blockIdx.y;
    int head = hs + z;
    int tid = threadIdx.x;
    int row = tid >> 2, cg = (tid & 3) * 16;
    size_t pb0 = (size_t)z * NTRI_ + (size_t)tb * (tb + 1) / 2;
    float M = -1e30f;
    for (int st = 0; st <= tb; st++)
        M = fmaxf(M, ml[(pb0 + st) * 128 + row]);
    float acc[16] = {};
    float lsum = 0.f;
    for (int st = 0; st <= tb; st++) {
        float mp = ml[(pb0 + st) * 128 + row];
        float lp = ml[(pb0 + st) * 128 + 64 + row];
        float sc = __expf(mp - M);
        lsum += lp * sc;
        const ushort_t* op = Op + (pb0 + st) * 4096 + (size_t)row * 64 + cg;
#pragma unroll
        for (int i = 0; i < 16; i++) acc[i] += bf2f(op[i]) * sc;
    }
    float inv = 1.f / lsum;
    int t = tb * 64 + row;
    ushort_t* dst = of + (size_t)t * D_ + (size_t)head * 64 + cg;
#pragma unroll
    for (int i = 0; i < 16; i++) dst[i] = f2bf(acc[i] * inv);
}

// ---------------------------------------------------------------------------
extern "C" void kernel_launch(void* const* d_in, const int* in_sizes, int n_in,
                              void* d_out, int out_size, void* d_ws, size_t ws_size,
                              hipStream_t stream)
{
    const float* h     = (const float*)d_in[0];
    const float* Wq    = (const float*)d_in[1];
    const float* Wk    = (const float*)d_in[2];
    const float* Wv    = (const float*)d_in[3];
    const float* Ww1   = (const float*)d_in[4];
    const float* Ww2   = (const float*)d_in[5];
    const float* convw = (const float*)d_in[6];
    const float* Wbt   = (const float*)d_in[7];
    const float* bbt   = (const float*)d_in[8];
    const float* Wg    = (const float*)d_in[9];
    const float* bgp   = (const float*)d_in[10];
    const float* Wo    = (const float*)d_in[11];
    float* out = (float*)d_out;

    float* ws = (float*)d_ws;
    size_t off = 0;
    auto allocF = [&](size_t nf) { float* p = ws + off; off += (nf + 1023) & ~(size_t)1023; return p; };

    // ---- persistent region (lives across the whole launch) ----
    float*    betaB = allocF((size_t)T_ * H_);
    float*    Gb    = allocF((size_t)T_ * H_);
    ushort_t* h_bf  = (ushort_t*)allocF(TD_ / 2);   // reused as of_bf after QKV GEMM
    ushort_t* of_bf = h_bf;
    ushort_t* w1bf  = (ushort_t*)allocF((size_t)T_ * 32 / 2);
    ushort_t* Ww2t  = (ushort_t*)allocF((size_t)D_ * 32 / 2);
    ushort_t* qkv   = (ushort_t*)allocF((size_t)3 * TD_ / 2);
    ushort_t* qh    = qkv;
    ushort_t* kh    = qkv + TD_;
    ushort_t* vt    = qkv + 2 * TD_;
    ushort_t* wh    = (ushort_t*)allocF(TD_ / 2);

    size_t scrOff = off;            // start of the overlaid scratch region
    size_t capF = ws_size / 4;

    // ---- phase A scratch (projection prep; dead before the chunk loop) ----
    float*    wr  = allocF(TD_);
    float*    s96 = allocF((size_t)T_ * 128);
    ushort_t* Wtc = (ushort_t*)allocF((size_t)6272 * D_ / 2);   // QKV + 96-pack

    // ---- phase B scratch overlays phase A (per-head chunk buffers) ----
    // perHead: ELb (L then Em) + Ct (TT_ bf16 each) + triangular Op + Mv + ml
    int NH = 32;
    ushort_t *ELb, *Ct, *OpB, *Mv;
    float* mlB;
    for (;;) {
        off = scrOff;
        ELb = (ushort_t*)allocF((size_t)NH * TT_ / 2);            // L, then Em
        Ct  = (ushort_t*)allocF((size_t)NH * TT_ / 2);
        OpB = (ushort_t*)allocF((size_t)NH * NTRI_ * 4096 / 2);   // triangular partials
        Mv  = (ushort_t*)allocF((size_t)NH * 16 * 4096 / 2);
        mlB = allocF((size_t)NH * NTRI_ * 128);
        if (off <= capF || NH == 1) break;
        NH >>= 1;
    }

    // ---- phase C scratch: Wo^T overlays phase B (all per-head dead) ----
    ushort_t* WoT = (ushort_t*)(ws + scrOff);

    dim3 blk(256);
    dim3 tcvB(32, 8);
    dim3 tcvG(D_ / 32, D_ / 32);

    // fused QKV + 96-proj via one MFMA GEMM (N = 6272)
    convert_bf16<<<dim3((TD_ + 255) / 256), blk, 0, stream>>>(h, h_bf, (int)TD_);
    transpose_convert<<<tcvG, tcvB, 0, stream>>>(Wq, Wtc, D_, D_);
    transpose_convert<<<tcvG, tcvB, 0, stream>>>(Wk, Wtc + (size_t)D_ * D_, D_, D_);
    transpose_convert<<<tcvG, tcvB, 0, stream>>>(Wv, Wtc + (size_t)2 * D_ * D_, D_, D_);
    pack96<<<dim3(128, 8), blk, 0, stream>>>(Ww1, Wbt, Wg, Wtc + (size_t)3 * D_ * D_);
    mfma_gemm<3><<<dim3(6272 / 128, T_ / 128), blk, 0, stream>>>(
        h_bf, Wtc, qkv, s96, T_, 6272, D_);

    // gates + w path
    bg96<<<dim3(T_ * 128 / 256), blk, 0, stream>>>(s96, bbt, bgp, w1bf, betaB, Gb);
    scan_g<<<dim3(H_), blk, 0, stream>>>(Gb);
    transpose_convert<<<dim3(D_ / 32, 1), tcvB, 0, stream>>>(Ww2, Ww2t, 32, D_);
    mfma_gemm<0><<<dim3(D_ / 128, T_ / 128), blk, 0, stream>>>(
        w1bf, Ww2t, wr, nullptr, T_, D_, 32);
    conv_silu_norm<<<dim3(T_ * H_), dim3(64), 0, stream>>>(wr, convw, wh);

    int nChunks = H_ / NH;
    for (int c = 0; c < nChunks; c++) {
        int hs = c * NH;
        pairdotLC<<<dim3(16, 16, NH), blk, 0, stream>>>(kh, wh, betaB, ELb, Ct, hs);
        diag_inv<<<dim3(16, NH), dim3(64), 0, stream>>>(ELb, Mv);
        solve_mfma<<<dim3(16, NH), blk, 0, stream>>>(Ct, ELb, Mv);
        pairdotE<<<dim3(16, 16, NH), blk, 0, stream>>>(qh, wh, betaB, ELb, hs);
        flash_split<<<dim3(16, 16, NH), blk, 0, stream>>>(
            qh, kh, vt, ELb, Ct, Gb, OpB, mlB, hs);
        combine<<<dim3(16, NH), blk, 0, stream>>>(OpB, mlB, of_bf, hs);
    }

    // out = of @ Wo via MFMA
    transpose_convert<<<tcvG, tcvB, 0, stream>>>(Wo, WoT, D_, D_);
    mfma_gemm<0><<<dim3(D_ / 128, T_ / 128), blk, 0, stream>>>(
        of_bf, WoT, out, nullptr, T_, D_, D_);
}

// Round 4
// 710.179 us; speedup vs baseline: 1.2456x; 1.1798x over previous
//
#include <hip/hip_runtime.h>
#include <hip/hip_bf16.h>

typedef __hip_bfloat16 bf16;
typedef unsigned short ushort_t;

#define T_  1024
#define D_  2048
#define H_  32
#define HD_ 64
#define NTRI_ 136   // 16*17/2 lower-triangular tile pairs

static const size_t TT_ = (size_t)T_ * T_;
static const size_t TD_ = (size_t)T_ * D_;

__device__ __forceinline__ ushort_t f2bf(float v) {
    bf16 b = __float2bfloat16(v);
    return *(ushort_t*)&b;
}
__device__ __forceinline__ float bf2f(ushort_t u) {
    bf16 b = *(bf16*)&u;
    return __bfloat162float(b);
}

// decode tri -> (st, tb) with tri = tb*(tb+1)/2 + st, st <= tb
__device__ __forceinline__ void tri_decode(int tri, int& st, int& tb) {
    int t = (int)((sqrtf(8.f * (float)tri + 1.f) - 1.f) * 0.5f);
    if (t * (t + 1) / 2 > tri) t--;
    if ((t + 1) * (t + 2) / 2 <= tri) t++;
    st = tri - t * (t + 1) / 2;
    tb = t;
}

typedef __attribute__((ext_vector_type(8))) short frag8;
typedef __attribute__((ext_vector_type(4))) float f32x4;
typedef __attribute__((ext_vector_type(4))) unsigned short u16x4;
typedef __attribute__((ext_vector_type(8))) unsigned short u16x8;

#define MFMA16(a, b, c) __builtin_amdgcn_mfma_f32_16x16x32_bf16((a), (b), (c), 0, 0, 0)

// ---------------------------------------------------------------------------
// MFMA GEMM: C = A[M,K]bf16 @ Bt[N,K]^T. 128x128 tile, BK=32.
// OUT: 0 = f32 row-major [M,N]
//      3 = packed QKV+small: col<2048 -> qh head-major bf16; <4096 -> kh;
//          <6144 -> vt transposed [head][64][T]; >=6144 -> Cout2 f32 [M][128]
// ---------------------------------------------------------------------------
template <int OUT>
__global__ __launch_bounds__(256) void mfma_gemm(
    const ushort_t* __restrict__ A, const ushort_t* __restrict__ Bt,
    void* __restrict__ Cout, void* __restrict__ Cout2, int M, int N, int K)
{
    __shared__ short Al[128 * 32];
    __shared__ short Bl[128 * 32];
    int tid = threadIdx.x;
    int w = tid >> 6, l = tid & 63;
    int row0 = blockIdx.y * 128, col0 = blockIdx.x * 128;
    int mq = (w >> 1) * 64, nq = (w & 1) * 64;
    int lm = l & 15, kq = l >> 4;
    f32x4 acc[4][4] = {};
    const ushort_t* Ap = A + (size_t)row0 * K;
    const ushort_t* Bp = Bt + (size_t)col0 * K;
    for (int kk = 0; kk < K; kk += 32) {
        __syncthreads();
#pragma unroll
        for (int r = 0; r < 2; r++) {
            int c = r * 256 + w * 64 + l;
            int row = c >> 2, kc = (c & 3) * 8;
            const ushort_t* ga = Ap + (size_t)row * K + kk + kc;
            const ushort_t* gb = Bp + (size_t)row * K + kk + kc;
            short* la = Al + (size_t)(r * 256 + w * 64) * 8;
            short* lb = Bl + (size_t)(r * 256 + w * 64) * 8;
            __builtin_amdgcn_global_load_lds((const __attribute__((address_space(1))) void*)ga,
                                             (__attribute__((address_space(3))) void*)la, 16, 0, 0);
            __builtin_amdgcn_global_load_lds((const __attribute__((address_space(1))) void*)gb,
                                             (__attribute__((address_space(3))) void*)lb, 16, 0, 0);
        }
        __builtin_amdgcn_s_waitcnt(0);
        __syncthreads();
        frag8 af[4], bfg[4];
#pragma unroll
        for (int i = 0; i < 4; i++)
            af[i] = *(const frag8*)&Al[(size_t)(mq + i * 16 + lm) * 32 + kq * 8];
#pragma unroll
        for (int j = 0; j < 4; j++)
            bfg[j] = *(const frag8*)&Bl[(size_t)(nq + j * 16 + lm) * 32 + kq * 8];
#pragma unroll
        for (int i = 0; i < 4; i++)
#pragma unroll
            for (int j = 0; j < 4; j++)
                acc[i][j] = MFMA16(af[i], bfg[j], acc[i][j]);
    }
#pragma unroll
    for (int i = 0; i < 4; i++)
#pragma unroll
        for (int j = 0; j < 4; j++)
#pragma unroll
            for (int r = 0; r < 4; r++) {
                int row = row0 + mq + i * 16 + kq * 4 + r;
                int col = col0 + nq + j * 16 + lm;
                float v = acc[i][j][r];
                if (OUT == 0) {
                    ((float*)Cout)[(size_t)row * N + col] = v;
                } else {
                    ushort_t* q = (ushort_t*)Cout;
                    int which = col >> 11, cl = col & 2047;
                    int hd = cl >> 6, d = cl & 63;
                    if (which == 0)
                        q[((size_t)hd * M + row) * 64 + d] = f2bf(v);
                    else if (which == 1)
                        q[(size_t)M * 2048 + ((size_t)hd * M + row) * 64 + d] = f2bf(v);
                    else if (which == 2)
                        q[(size_t)M * 4096 + ((size_t)hd * 64 + d) * M + row] = f2bf(v);
                    else
                        ((float*)Cout2)[(size_t)row * 128 + (col - 6144)] = v;
                }
            }
}

// ---------------------------------------------------------------------------
__global__ void transpose_convert(const float* __restrict__ W, ushort_t* __restrict__ Wt,
                                  int R, int Cc)
{
    __shared__ float tile[32][33];
    int bx = blockIdx.x * 32, by = blockIdx.y * 32;
    int tx = threadIdx.x, ty = threadIdx.y;
    for (int i = ty; i < 32; i += 8)
        tile[i][tx] = W[(size_t)(by + i) * Cc + bx + tx];
    __syncthreads();
    for (int i = ty; i < 32; i += 8)
        Wt[(size_t)(bx + i) * R + by + tx] = f2bf(tile[tx][i]);
}

// pack Ww1^T/Wbt^T/Wg^T (+zero pad) into rows [0..128) of dst[128][2048]
__global__ void pack96(const float* __restrict__ Ww1, const float* __restrict__ Wbt,
                       const float* __restrict__ Wg, ushort_t* __restrict__ dst)
{
    int r = blockIdx.x;
    int k = blockIdx.y * 256 + threadIdx.x;
    float v = 0.f;
    if (r < 32)       v = Ww1[(size_t)k * 32 + r];
    else if (r < 64)  v = Wbt[(size_t)k * 32 + (r - 32)];
    else if (r < 96)  v = Wg[(size_t)k * 32 + (r - 64)];
    dst[(size_t)r * 2048 + k] = f2bf(v);
}

__global__ void convert_bf16(const float* __restrict__ in, ushort_t* __restrict__ out, int n)
{
    int i = blockIdx.x * 256 + threadIdx.x;
    if (i < n) out[i] = f2bf(in[i]);
}

// epilogue of the 96-proj: w1 bf16, beta, G(pre-scan)
__global__ void bg96(const float* __restrict__ s96, const float* __restrict__ bbt,
                     const float* __restrict__ bgp, ushort_t* __restrict__ w1bf,
                     float* __restrict__ betaB, float* __restrict__ Gb)
{
    int idx = blockIdx.x * 256 + threadIdx.x;   // over T_*128
    int t = idx >> 7, o = idx & 127;
    if (o >= 96) return;
    float v = s96[(size_t)t * 128 + o];
    if (o < 32) {
        w1bf[(size_t)t * 32 + o] = f2bf(v);
    } else if (o < 64) {
        float xb = v + bbt[o - 32];
        betaB[(size_t)t * H_ + (o - 32)] = 2.f / (1.f + expf(-xb));
    } else {
        float xg = v + bgp[o - 64];
        Gb[(size_t)t * H_ + (o - 64)] =
            (xg >= 0.f) ? -log1pf(expf(-xg)) : (xg - log1pf(expf(xg)));
    }
}

// parallel inclusive scan of G[:, h] per head. Grid (H_), block 256.
__global__ void scan_g(float* __restrict__ G)
{
    int h = blockIdx.x;
    int tid = threadIdx.x;
    __shared__ float psum[256];
    float v[4];
    float s = 0.f;
#pragma unroll
    for (int r = 0; r < 4; r++) {
        v[r] = G[(size_t)(tid * 4 + r) * H_ + h];
        s += v[r];
    }
    psum[tid] = s;
    __syncthreads();
    for (int off = 1; off < 256; off <<= 1) {
        float t = (tid >= off) ? psum[tid - off] : 0.f;
        __syncthreads();
        psum[tid] += t;
        __syncthreads();
    }
    float run = (tid > 0) ? psum[tid - 1] : 0.f;
#pragma unroll
    for (int r = 0; r < 4; r++) {
        run += v[r];
        G[(size_t)(tid * 4 + r) * H_ + h] = run;
    }
}

// conv(3) + silu + l2norm -> wh bf16 head-major [H][T][64]
__global__ void conv_silu_norm(const float* __restrict__ wr, const float* __restrict__ convw,
                               ushort_t* __restrict__ wh)
{
    int b = blockIdx.x;
    int t = b >> 5, h = b & 31;
    int d = threadIdx.x;
    int c = h * 64 + d;
    float c0 = convw[c * 3 + 0];
    float c1 = convw[c * 3 + 1];
    float c2 = convw[c * 3 + 2];
    float x = c2 * wr[(size_t)t * D_ + c];
    if (t >= 1) x += c1 * wr[(size_t)(t - 1) * D_ + c];
    if (t >= 2) x += c0 * wr[(size_t)(t - 2) * D_ + c];
    float y = x / (1.f + expf(-x));
    float ss = y * y;
    for (int off = 32; off > 0; off >>= 1) ss += __shfl_xor(ss, off, 64);
    wh[((size_t)h * T_ + t) * 64 + d] = f2bf(y * rsqrtf(ss));
}

// ---------------------------------------------------------------------------
// pairdotLC: per lower tile (t0,s0):
//   L[t][s]  = strict(w_t.w_s)*beta[s]   (bf16 row-major, into ELb)
//   Ct[s][t] = strict(w_t.k_s)           (bf16 TRANSPOSED [s][t])
// Grid (NTRI_, NH), triangular-dense.
// ---------------------------------------------------------------------------
__global__ __launch_bounds__(256) void pairdotLC(
    const ushort_t* __restrict__ kh, const ushort_t* __restrict__ wh,
    const float* __restrict__ betaB,
    ushort_t* __restrict__ ELb, ushort_t* __restrict__ Ct, int hs)
{
    int st, tb;
    tri_decode(blockIdx.x, st, tb);
    int s0 = st * 64, t0 = tb * 64, z = blockIdx.y;
    int head = hs + z;
    const ushort_t* kb = kh + (size_t)head * T_ * 64;
    const ushort_t* wb = wh + (size_t)head * T_ * 64;
    ushort_t* Lz = ELb + (size_t)z * TT_;
    ushort_t* Cz = Ct + (size_t)z * TT_;
    int tid = threadIdx.x;
    int w = tid >> 6, l = tid & 63;
    int lm = l & 15, kq = l >> 4;
    int rowA = t0 + w * 16 + lm;
    f32x4 accL[4] = {}, accS[4] = {};
#pragma unroll
    for (int kk = 0; kk < 64; kk += 32) {
        frag8 aw = *(const frag8*)&wb[(size_t)rowA * 64 + kk + kq * 8];
#pragma unroll
        for (int j = 0; j < 4; j++) {
            int colr = s0 + j * 16 + lm;
            frag8 bw = *(const frag8*)&wb[(size_t)colr * 64 + kk + kq * 8];
            frag8 bk = *(const frag8*)&kb[(size_t)colr * 64 + kk + kq * 8];
            accL[j] = MFMA16(aw, bw, accL[j]);
            accS[j] = MFMA16(aw, bk, accS[j]);
        }
    }
    int m0 = w * 16 + kq * 4;
#pragma unroll
    for (int j = 0; j < 4; j++) {
        int s = s0 + j * 16 + lm;
        float beta = betaB[(size_t)s * H_ + head];
        ushort_t cl[4];
#pragma unroll
        for (int r = 0; r < 4; r++) {
            int t = t0 + m0 + r;
            Lz[(size_t)t * T_ + s] = f2bf((s < t) ? accL[j][r] * beta : 0.f);
            cl[r] = f2bf((s < t) ? accS[j][r] : 0.f);
        }
        *(u16x4*)&Cz[(size_t)s * T_ + t0 + m0] = *(u16x4*)cl;
    }
}

// pairdotE: Em[t][s] = -causal(q_t.w_s)*beta[s] into ELb (L dead post-solve)
// Grid (NTRI_, NH), triangular-dense.
__global__ __launch_bounds__(256) void pairdotE(
    const ushort_t* __restrict__ qh, const ushort_t* __restrict__ wh,
    const float* __restrict__ betaB, ushort_t* __restrict__ ELb, int hs)
{
    int st, tb;
    tri_decode(blockIdx.x, st, tb);
    int s0 = st * 64, t0 = tb * 64, z = blockIdx.y;
    int head = hs + z;
    const ushort_t* qb = qh + (size_t)head * T_ * 64;
    const ushort_t* wb = wh + (size_t)head * T_ * 64;
    ushort_t* Ez = ELb + (size_t)z * TT_;
    int tid = threadIdx.x;
    int w = tid >> 6, l = tid & 63;
    int lm = l & 15, kq = l >> 4;
    int rowA = t0 + w * 16 + lm;
    f32x4 accE[4] = {};
#pragma unroll
    for (int kk = 0; kk < 64; kk += 32) {
        frag8 aq = *(const frag8*)&qb[(size_t)rowA * 64 + kk + kq * 8];
#pragma unroll
        for (int j = 0; j < 4; j++) {
            frag8 bw = *(const frag8*)&wb[(size_t)(s0 + j * 16 + lm) * 64 + kk + kq * 8];
            accE[j] = MFMA16(aq, bw, accE[j]);
        }
    }
    int m0 = w * 16 + kq * 4;
#pragma unroll
    for (int j = 0; j < 4; j++) {
        int s = s0 + j * 16 + lm;
        float beta = betaB[(size_t)s * H_ + head];
#pragma unroll
        for (int r = 0; r < 4; r++) {
            int t = t0 + m0 + r;
            Ez[(size_t)t * T_ + s] = f2bf((s <= t) ? -accE[j][r] * beta : 0.f);
        }
    }
}

// ---------------------------------------------------------------------------
// diag_inv: invert 64x64 unit-lower diag blocks of (I + L); Minv bf16 out.
// ---------------------------------------------------------------------------
__global__ void diag_inv(const ushort_t* __restrict__ Lb, ushort_t* __restrict__ Minv)
{
    int bi = blockIdx.x, z = blockIdx.y;
    const ushort_t* Lh = Lb + (size_t)z * TT_;
    __shared__ float Nb[64][65];
    __shared__ float Xc[64][65];
    int tid = threadIdx.x;
    for (int i = tid; i < 4096; i += 64) {
        int r = i >> 6, c = i & 63;
        Nb[r][c] = (c < r) ? bf2f(Lh[(size_t)(bi * 64 + r) * T_ + bi * 64 + c]) : 0.f;
    }
    __syncthreads();
    int j = tid;
    for (int t = 0; t < 64; t++) {
        float v = (t == j) ? 1.f : 0.f;
        for (int i = j; i < t; i++) v -= Nb[t][i] * Xc[i][j];
        Xc[t][j] = v;
    }
    __syncthreads();
    ushort_t* Mo = Minv + ((size_t)z * 16 + bi) * 4096;
    for (int i = tid; i < 4096; i += 64) Mo[i] = f2bf(Xc[i >> 6][i & 63]);
}

// ---------------------------------------------------------------------------
// solve_mfma: block-forward solve for one 64-col strip.
// Latency-pipelined: register-batched staging, 1-chunk-ahead register
// prefetch (A/B sets), cross-step chunk0 prefetch, hoisted Minv/rhs loads.
// Grid (16, NH), block 256.
// ---------------------------------------------------------------------------
__global__ __launch_bounds__(256) void solve_mfma(
    ushort_t* __restrict__ Ct, const ushort_t* __restrict__ Lb,
    const ushort_t* __restrict__ Minv)
{
    int ct = blockIdx.x, z = blockIdx.y;
    ushort_t* Cz = Ct + (size_t)z * TT_;
    const ushort_t* Lz = Lb + (size_t)z * TT_;
    __shared__ ushort_t Cl[64][136];
    __shared__ ushort_t Ll[64][136];
    __shared__ ushort_t Xbt[64][72];
    int tid = threadIdx.x;
    int w = tid >> 6, l = tid & 63;
    int lm = l & 15, kq = l >> 4;
    int s0 = ct * 64;
    int m0 = w * 16 + kq * 4;

    u16x8 cA[4], lA[4], cB[4], lB[4];

    // issue all chunk loads back-to-back into regs (no intervening waits)
    auto issue = [&](u16x8 (&rc)[4], u16x8 (&rl)[4], int kkc, int lrow, int lsh) {
#pragma unroll
        for (int t = 0; t < 4; t++) {
            int i = tid + t * 256;
            if (i < (64 << lsh)) {
                int r = i >> lsh, c = (i & ((1 << lsh) - 1)) * 8;
                rc[t] = *(const u16x8*)&Cz[(size_t)(s0 + r) * T_ + kkc + c];
                rl[t] = *(const u16x8*)&Lz[(size_t)(lrow + r) * T_ + kkc + c];
            }
        }
    };
    auto stage = [&](u16x8 (&rc)[4], u16x8 (&rl)[4], int lsh) {
#pragma unroll
        for (int t = 0; t < 4; t++) {
            int i = tid + t * 256;
            if (i < (64 << lsh)) {
                int r = i >> lsh, c = (i & ((1 << lsh) - 1)) * 8;
                *(u16x8*)&Cl[r][c] = rc[t];
                *(u16x8*)&Ll[r][c] = rl[t];
            }
        }
    };
    auto compute = [&](int len, f32x4 (&acc)[4]) {
        for (int kk2 = 0; kk2 < len; kk2 += 32) {
            frag8 a = *(const frag8*)&Ll[w * 16 + lm][kk2 + kq * 8];
#pragma unroll
            for (int j = 0; j < 4; j++) {
                frag8 b = *(const frag8*)&Cl[j * 16 + lm][kk2 + kq * 8];
                acc[j] = MFMA16(a, b, acc[j]);
            }
        }
    };

    bool pre0 = false;
    for (int bi = ct; bi < 16; bi++) {
        int kend = bi * 64;   // also the L block-row base for this step
        const ushort_t* Mo = Minv + ((size_t)z * 16 + bi) * 4096;
        frag8 ma0 = *(const frag8*)&Mo[(size_t)(w * 16 + lm) * 64 + kq * 8];
        frag8 ma1 = *(const frag8*)&Mo[(size_t)(w * 16 + lm) * 64 + 32 + kq * 8];
        u16x4 rhs[4];
#pragma unroll
        for (int j = 0; j < 4; j++)
            rhs[j] = *(const u16x4*)&Cz[(size_t)(s0 + j * 16 + lm) * T_ + kend + m0];

        f32x4 acc[4] = {};
        int kkc = s0;
        bool haveA = pre0;
        while (kkc < kend) {
            int len = kend - kkc; if (len > 128) len = 128;
            int lsh = (len == 128) ? 4 : 3;
            __syncthreads();
            if (!haveA) issue(cA, lA, kkc, kend, lsh);
            stage(cA, lA, lsh);
            bool nb = (kkc + 128 < kend);
            if (nb) {
                int len2 = kend - kkc - 128; if (len2 > 128) len2 = 128;
                issue(cB, lB, kkc + 128, kend, (len2 == 128) ? 4 : 3);
            }
            __syncthreads();
            compute(len, acc);
            kkc += 128;
            if (!nb) break;

            len = kend - kkc; if (len > 128) len = 128;
            lsh = (len == 128) ? 4 : 3;
            __syncthreads();
            stage(cB, lB, lsh);
            bool na = (kkc + 128 < kend);
            if (na) {
                int len2 = kend - kkc - 128; if (len2 > 128) len2 = 128;
                issue(cA, lA, kkc + 128, kend, (len2 == 128) ? 4 : 3);
            }
            __syncthreads();
            compute(len, acc);
            kkc += 128;
            haveA = na;
            if (!na) break;
        }

        // epilogue: X = rhs - acc, then res = Minv_diag @ X
#pragma unroll
        for (int j = 0; j < 4; j++) {
            ushort_t xb[4];
#pragma unroll
            for (int r = 0; r < 4; r++) xb[r] = f2bf(bf2f(rhs[j][r]) - acc[j][r]);
            *(u16x4*)&Xbt[j * 16 + lm][m0] = *(u16x4*)xb;
        }
        __syncthreads();
        pre0 = (bi + 1 < 16) && (bi - ct >= 2);
        if (pre0) issue(cA, lA, s0, (bi + 1) * 64, 4);
        f32x4 res[4] = {};
#pragma unroll
        for (int j = 0; j < 4; j++) {
            frag8 b0 = *(const frag8*)&Xbt[j * 16 + lm][kq * 8];
            frag8 b1 = *(const frag8*)&Xbt[j * 16 + lm][32 + kq * 8];
            res[j] = MFMA16(ma0, b0, res[j]);
            res[j] = MFMA16(ma1, b1, res[j]);
        }
#pragma unroll
        for (int j = 0; j < 4; j++) {
            int sc = s0 + j * 16 + lm;
            ushort_t cr[4];
#pragma unroll
            for (int r = 0; r < 4; r++) cr[r] = f2bf(res[j][r]);
            *(u16x4*)&Cz[(size_t)sc * T_ + kend + m0] = *(u16x4*)cr;
        }
    }
}

// ---------------------------------------------------------------------------
// flash_split: one triangular (s-tile, t-tile, head) per block.
//   x = q.k^T + sum_k Em[t,k] C[k,s]; single-tile softmax partial -> Op/ml.
// K/V/q fragments direct from global (no LDS); E/C chunks register-prefetched
// double-buffered. Grid (NTRI_, NH), block 256.
// ---------------------------------------------------------------------------
__global__ __launch_bounds__(256) void flash_split(
    const ushort_t* __restrict__ qh, const ushort_t* __restrict__ kh,
    const ushort_t* __restrict__ vt, const ushort_t* __restrict__ Em,
    const ushort_t* __restrict__ Ct, const float* __restrict__ Gb,
    ushort_t* __restrict__ Op, float* __restrict__ ml, int hs)
{
    int st, tb;
    int tri = blockIdx.x;
    tri_decode(tri, st, tb);
    int t0 = tb * 64, s0 = st * 64, z = blockIdx.y;
    int head = hs + z;
    const ushort_t* qb = qh + (size_t)head * T_ * 64;
    const ushort_t* kb = kh + (size_t)head * T_ * 64;
    const ushort_t* vb = vt + (size_t)head * 64 * T_;
    const ushort_t* Ez = Em + (size_t)z * TT_;
    const ushort_t* Cz = Ct + (size_t)z * TT_;
    __shared__ ushort_t El[64][72];
    __shared__ ushort_t Cl[64][72];
    __shared__ ushort_t Pl[4][16][76];
    int tid = threadIdx.x;
    int w = tid >> 6, l = tid & 63;
    int lm = l & 15, kq = l >> 4;
    int rowA = t0 + w * 16 + lm;
    int m0 = w * 16 + kq * 4;

    u16x8 eA[2], cA[2], eB[2], cB[2];
    auto issueEC = [&](u16x8 (&re)[2], u16x8 (&rc)[2], int kc) {
#pragma unroll
        for (int t = 0; t < 2; t++) {
            int i = tid + t * 256;
            int r = i >> 3, cc = (i & 7) * 8;
            re[t] = *(const u16x8*)&Ez[(size_t)(t0 + r) * T_ + kc + cc];
            rc[t] = *(const u16x8*)&Cz[(size_t)(s0 + r) * T_ + kc + cc];
        }
    };
    auto stageEC = [&](u16x8 (&re)[2], u16x8 (&rc)[2]) {
#pragma unroll
        for (int t = 0; t < 2; t++) {
            int i = tid + t * 256;
            int r = i >> 3, cc = (i & 7) * 8;
            *(u16x8*)&El[r][cc] = re[t];
            *(u16x8*)&Cl[r][cc] = rc[t];
        }
    };

    // prefetch first E/C chunk immediately so latency hides under QK^T
    issueEC(eA, cA, s0);

    // q and K fragments direct from global
    frag8 aq0 = *(const frag8*)&qb[(size_t)rowA * 64 + kq * 8];
    frag8 aq1 = *(const frag8*)&qb[(size_t)rowA * 64 + 32 + kq * 8];
    f32x4 x[4] = {};
#pragma unroll
    for (int j = 0; j < 4; j++) {
        frag8 b0 = *(const frag8*)&kb[(size_t)(s0 + j * 16 + lm) * 64 + kq * 8];
        frag8 b1 = *(const frag8*)&kb[(size_t)(s0 + j * 16 + lm) * 64 + 32 + kq * 8];
        x[j] = MFMA16(aq0, b0, x[j]);
        x[j] = MFMA16(aq1, b1, x[j]);
    }

    // correction: x += sum over k-chunks of Em(t,k) * C(k,s), pipelined
    int nc = tb - st + 1;
    bool useA = true;
    for (int ci = 0; ci < nc; ci++) {
        __syncthreads();                 // prev chunk's LDS reads done
        if (useA) stageEC(eA, cA); else stageEC(eB, cB);
        if (ci + 1 < nc) {
            int kc = s0 + (ci + 1) * 64;
            if (useA) issueEC(eB, cB, kc); else issueEC(eA, cA, kc);
        }
        __syncthreads();
#pragma unroll
        for (int kk2 = 0; kk2 < 64; kk2 += 32) {
            frag8 a = *(const frag8*)&El[w * 16 + lm][kk2 + kq * 8];
#pragma unroll
            for (int j = 0; j < 4; j++) {
                frag8 b = *(const frag8*)&Cl[j * 16 + lm][kk2 + kq * 8];
                x[j] = MFMA16(a, b, x[j]);
            }
        }
        useA = !useA;
    }

    // V fragments direct from global; latency hides under softmax VALU
    frag8 vf0[4], vf1[4];
#pragma unroll
    for (int j = 0; j < 4; j++) {
        vf0[j] = *(const frag8*)&vb[(size_t)(j * 16 + lm) * T_ + s0 + kq * 8];
        vf1[j] = *(const frag8*)&vb[(size_t)(j * 16 + lm) * T_ + s0 + 32 + kq * 8];
    }

    // single-tile softmax partial
    float lg[4][4];
#pragma unroll
    for (int j = 0; j < 4; j++) {
        int s = s0 + j * 16 + lm;
        float g = Gb[(size_t)s * H_ + head];
#pragma unroll
        for (int r = 0; r < 4; r++) {
            int t = t0 + m0 + r;
            lg[j][r] = (s <= t) ? (x[j][r] * 0.125f - g) : -1e30f;
        }
    }
    float mrow[4];
#pragma unroll
    for (int r = 0; r < 4; r++)
        mrow[r] = fmaxf(fmaxf(lg[0][r], lg[1][r]), fmaxf(lg[2][r], lg[3][r]));
#pragma unroll
    for (int d = 1; d < 16; d <<= 1)
#pragma unroll
        for (int r = 0; r < 4; r++) mrow[r] = fmaxf(mrow[r], __shfl_xor(mrow[r], d, 64));
    float lrow[4] = {0.f, 0.f, 0.f, 0.f};
#pragma unroll
    for (int j = 0; j < 4; j++)
#pragma unroll
        for (int r = 0; r < 4; r++) {
            float p = __expf(lg[j][r] - mrow[r]);
            lg[j][r] = p;
            lrow[r] += p;
        }
#pragma unroll
    for (int d = 1; d < 16; d <<= 1)
#pragma unroll
        for (int r = 0; r < 4; r++) lrow[r] += __shfl_xor(lrow[r], d, 64);
    // P -> per-wave slab (same-wave ordering), O = P @ V
#pragma unroll
    for (int j = 0; j < 4; j++)
#pragma unroll
        for (int r = 0; r < 4; r++)
            Pl[w][kq * 4 + r][j * 16 + lm] = f2bf(lg[j][r]);
    f32x4 o[4] = {};
#pragma unroll
    for (int j = 0; j < 4; j++) {
        frag8 a0 = *(const frag8*)&Pl[w][lm][kq * 8];
        frag8 a1 = *(const frag8*)&Pl[w][lm][32 + kq * 8];
        o[j] = MFMA16(a0, vf0[j], o[j]);
        o[j] = MFMA16(a1, vf1[j], o[j]);
    }
    size_t pbase = ((size_t)z * NTRI_ + tri) * 4096;
#pragma unroll
    for (int j = 0; j < 4; j++)
#pragma unroll
        for (int r = 0; r < 4; r++)
            Op[pbase + (size_t)(m0 + r) * 64 + j * 16 + lm] = f2bf(o[j][r]);
    if (lm == 0) {
        size_t mbase = ((size_t)z * NTRI_ + tri) * 128;
#pragma unroll
        for (int r = 0; r < 4; r++) {
            ml[mbase + m0 + r] = mrow[r];
            ml[mbase + 64 + m0 + r] = lrow[r];
        }
    }
}

// ---------------------------------------------------------------------------
// combine: merge <=16 partials per (t-tile, head) -> of bf16.
// ---------------------------------------------------------------------------
__global__ __launch_bounds__(256) void combine(
    const ushort_t* __restrict__ Op, const float* __restrict__ ml,
    ushort_t* __restrict__ of, int hs)
{
    int tb = blockIdx.x, z = blockIdx.y;
    int head = hs + z;
    int tid = threadIdx.x;
    int row = tid >> 2, cg = (tid & 3) * 16;
    size_t pb0 = (size_t)z * NTRI_ + (size_t)tb * (tb + 1) / 2;
    float M = -1e30f;
    for (int st = 0; st <= tb; st++)
        M = fmaxf(M, ml[(pb0 + st) * 128 + row]);
    float acc[16] = {};
    float lsum = 0.f;
    for (int st = 0; st <= tb; st++) {
        float mp = ml[(pb0 + st) * 128 + row];
        float lp = ml[(pb0 + st) * 128 + 64 + row];
        float sc = __expf(mp - M);
        lsum += lp * sc;
        const ushort_t* op = Op + (pb0 + st) * 4096 + (size_t)row * 64 + cg;
#pragma unroll
        for (int i = 0; i < 16; i++) acc[i] += bf2f(op[i]) * sc;
    }
    float inv = 1.f / lsum;
    int t = tb * 64 + row;
    ushort_t* dst = of + (size_t)t * D_ + (size_t)head * 64 + cg;
#pragma unroll
    for (int i = 0; i < 16; i++) dst[i] = f2bf(acc[i] * inv);
}

// ---------------------------------------------------------------------------
extern "C" void kernel_launch(void* const* d_in, const int* in_sizes, int n_in,
                              void* d_out, int out_size, void* d_ws, size_t ws_size,
                              hipStream_t stream)
{
    const float* h     = (const float*)d_in[0];
    const float* Wq    = (const float*)d_in[1];
    const float* Wk    = (const float*)d_in[2];
    const float* Wv    = (const float*)d_in[3];
    const float* Ww1   = (const float*)d_in[4];
    const float* Ww2   = (const float*)d_in[5];
    const float* convw = (const float*)d_in[6];
    const float* Wbt   = (const float*)d_in[7];
    const float* bbt   = (const float*)d_in[8];
    const float* Wg    = (const float*)d_in[9];
    const float* bgp   = (const float*)d_in[10];
    const float* Wo    = (const float*)d_in[11];
    float* out = (float*)d_out;

    float* ws = (float*)d_ws;
    size_t off = 0;
    auto allocF = [&](size_t nf) { float* p = ws + off; off += (nf + 1023) & ~(size_t)1023; return p; };

    // ---- persistent region (lives across the whole launch) ----
    float*    betaB = allocF((size_t)T_ * H_);
    float*    Gb    = allocF((size_t)T_ * H_);
    ushort_t* h_bf  = (ushort_t*)allocF(TD_ / 2);   // reused as of_bf after QKV GEMM
    ushort_t* of_bf = h_bf;
    ushort_t* w1bf  = (ushort_t*)allocF((size_t)T_ * 32 / 2);
    ushort_t* Ww2t  = (ushort_t*)allocF((size_t)D_ * 32 / 2);
    ushort_t* qkv   = (ushort_t*)allocF((size_t)3 * TD_ / 2);
    ushort_t* qh    = qkv;
    ushort_t* kh    = qkv + TD_;
    ushort_t* vt    = qkv + 2 * TD_;
    ushort_t* wh    = (ushort_t*)allocF(TD_ / 2);

    size_t scrOff = off;            // start of the overlaid scratch region
    size_t capF = ws_size / 4;

    // ---- phase A scratch (projection prep; dead before the chunk loop) ----
    float*    wr  = allocF(TD_);
    float*    s96 = allocF((size_t)T_ * 128);
    ushort_t* Wtc = (ushort_t*)allocF((size_t)6272 * D_ / 2);   // QKV + 96-pack

    // ---- phase B scratch overlays phase A (per-head chunk buffers) ----
    int NH = 32;
    ushort_t *ELb, *Ct, *OpB, *Mv;
    float* mlB;
    for (;;) {
        off = scrOff;
        ELb = (ushort_t*)allocF((size_t)NH * TT_ / 2);            // L, then Em
        Ct  = (ushort_t*)allocF((size_t)NH * TT_ / 2);
        OpB = (ushort_t*)allocF((size_t)NH * NTRI_ * 4096 / 2);   // triangular partials
        Mv  = (ushort_t*)allocF((size_t)NH * 16 * 4096 / 2);
        mlB = allocF((size_t)NH * NTRI_ * 128);
        if (off <= capF || NH == 1) break;
        NH >>= 1;
    }

    // ---- phase C scratch: Wo^T overlays phase B (all per-head dead) ----
    ushort_t* WoT = (ushort_t*)(ws + scrOff);

    dim3 blk(256);
    dim3 tcvB(32, 8);
    dim3 tcvG(D_ / 32, D_ / 32);

    // fused QKV + 96-proj via one MFMA GEMM (N = 6272)
    convert_bf16<<<dim3((TD_ + 255) / 256), blk, 0, stream>>>(h, h_bf, (int)TD_);
    transpose_convert<<<tcvG, tcvB, 0, stream>>>(Wq, Wtc, D_, D_);
    transpose_convert<<<tcvG, tcvB, 0, stream>>>(Wk, Wtc + (size_t)D_ * D_, D_, D_);
    transpose_convert<<<tcvG, tcvB, 0, stream>>>(Wv, Wtc + (size_t)2 * D_ * D_, D_, D_);
    pack96<<<dim3(128, 8), blk, 0, stream>>>(Ww1, Wbt, Wg, Wtc + (size_t)3 * D_ * D_);
    mfma_gemm<3><<<dim3(6272 / 128, T_ / 128), blk, 0, stream>>>(
        h_bf, Wtc, qkv, s96, T_, 6272, D_);

    // gates + w path
    bg96<<<dim3(T_ * 128 / 256), blk, 0, stream>>>(s96, bbt, bgp, w1bf, betaB, Gb);
    scan_g<<<dim3(H_), blk, 0, stream>>>(Gb);
    transpose_convert<<<dim3(D_ / 32, 1), tcvB, 0, stream>>>(Ww2, Ww2t, 32, D_);
    mfma_gemm<0><<<dim3(D_ / 128, T_ / 128), blk, 0, stream>>>(
        w1bf, Ww2t, wr, nullptr, T_, D_, 32);
    conv_silu_norm<<<dim3(T_ * H_), dim3(64), 0, stream>>>(wr, convw, wh);

    int nChunks = H_ / NH;
    for (int c = 0; c < nChunks; c++) {
        int hs = c * NH;
        pairdotLC<<<dim3(NTRI_, NH), blk, 0, stream>>>(kh, wh, betaB, ELb, Ct, hs);
        diag_inv<<<dim3(16, NH), dim3(64), 0, stream>>>(ELb, Mv);
        solve_mfma<<<dim3(16, NH), blk, 0, stream>>>(Ct, ELb, Mv);
        pairdotE<<<dim3(NTRI_, NH), blk, 0, stream>>>(qh, wh, betaB, ELb, hs);
        flash_split<<<dim3(NTRI_, NH), blk, 0, stream>>>(
            qh, kh, vt, ELb, Ct, Gb, OpB, mlB, hs);
        combine<<<dim3(16, NH), blk, 0, stream>>>(OpB, mlB, of_bf, hs);
    }

    // out = of @ Wo via MFMA
    transpose_convert<<<tcvG, tcvB, 0, stream>>>(Wo, WoT, D_, D_);
    mfma_gemm<0><<<dim3(D_ / 128, T_ / 128), blk, 0, stream>>>(
        of_bf, WoT, out, nullptr, T_, D_, D_);
}